// Round 1
// baseline (599.218 us; speedup 1.0000x reference)
//
#include <hip/hip_runtime.h>
#include <stdint.h>

// Problem constants (match reference)
#define NB  32     // B
#define NN  1024   // N
#define FIN 128
#define HH  64
#define CC  32

using short8  = __attribute__((ext_vector_type(8))) short;
using floatx4 = __attribute__((ext_vector_type(4))) float;

__device__ inline float b2f(unsigned short u) {
  union { uint32_t i; float f; } v; v.i = ((uint32_t)u) << 16; return v.f;
}
__device__ inline unsigned short f2b(float f) {
  union { uint32_t i; float f; } v; v.f = f;
  uint32_t r = v.i + 0x7FFFu + ((v.i >> 16) & 1u);
  return (unsigned short)(r >> 16);
}
__device__ inline floatx4 zf4() { floatx4 v = {0.f, 0.f, 0.f, 0.f}; return v; }

// ---------------------------------------------------------------------------
// k_convert: adj(int32) -> Abf(bf16), rowbits (bitset of each row), dinv
// grid = B*N blocks (one row each), 256 threads
// ---------------------------------------------------------------------------
__global__ __launch_bounds__(256) void k_convert(const int* __restrict__ adj,
    unsigned short* __restrict__ Abf, uint32_t* __restrict__ rowbits,
    float* __restrict__ dinv) {
  const int blk = blockIdx.x;                 // b*N + i
  const size_t base = (size_t)blk * NN;
  __shared__ uint32_t rw[32];
  __shared__ int wsum[4];
  const int t = threadIdx.x;
  if (t < 32) rw[t] = 0u;
  __syncthreads();
  int4 a = ((const int4*)(adj + base))[t];
  int b0 = (a.x != 0), b1 = (a.y != 0), b2 = (a.z != 0), b3 = (a.w != 0);
  ushort4 o;
  o.x = b0 ? 0x3F80 : 0; o.y = b1 ? 0x3F80 : 0;
  o.z = b2 ? 0x3F80 : 0; o.w = b3 ? 0x3F80 : 0;
  ((ushort4*)(Abf + base))[t] = o;
  uint32_t nib = ((uint32_t)(b0 | (b1 << 1) | (b2 << 2) | (b3 << 3))) << ((t & 7) * 4);
  atomicOr(&rw[t >> 3], nib);
  int s = b0 + b1 + b2 + b3;
  #pragma unroll
  for (int m = 1; m < 64; m <<= 1) s += __shfl_xor(s, m, 64);
  if ((t & 63) == 0) wsum[t >> 6] = s;
  __syncthreads();
  if (t < 32) rowbits[(size_t)blk * 32 + t] = rw[t];
  if (t == 0) {
    float deg = (float)(wsum[0] + wsum[1] + wsum[2] + wsum[3]) + 1.0f; // self-loop
    dinv[blk] = rsqrtf(deg);
  }
}

// ---------------------------------------------------------------------------
// k_colbits: column bitsets of adj. grid = B*4*4 (jt-tile of 256 cols, ks-quarter
// of rows -> 8 owned words), 256 threads (one column each)
// ---------------------------------------------------------------------------
__global__ __launch_bounds__(256) void k_colbits(const int* __restrict__ adj,
    uint32_t* __restrict__ colbits) {
  const int bid = blockIdx.x;                 // b*16 + jt*4 + ks
  const int b = bid >> 4, jt = (bid >> 2) & 3, ks = bid & 3;
  const int j = jt * 256 + threadIdx.x;
  const size_t base = (size_t)b * NN * NN;
  uint32_t w[8] = {0, 0, 0, 0, 0, 0, 0, 0};
  #pragma unroll 8
  for (int kk = 0; kk < 256; kk++) {
    int k = ks * 256 + kk;
    int v = adj[base + (size_t)k * NN + j];
    w[kk >> 5] |= ((uint32_t)(v != 0)) << (kk & 31);
  }
  uint32_t* dst = colbits + ((size_t)b * NN + j) * 32 + ks * 8;
  #pragma unroll
  for (int x = 0; x < 8; x++) dst[x] = w[x];
}

// ---------------------------------------------------------------------------
// k_xw: xs[j,:] = bf16(dinv_j * (x[j,:] @ W_gcn)); also transposed copy xst[H][N]
// grid = B*64 (16 rows each), 256 threads (4 groups of 64)
// ---------------------------------------------------------------------------
__global__ __launch_bounds__(256) void k_xw(const float* __restrict__ x,
    const float* __restrict__ Wg, const float* __restrict__ dinv,
    unsigned short* __restrict__ xs, unsigned short* __restrict__ xst) {
  __shared__ float WL[FIN * HH];
  __shared__ float xr[4][FIN];
  const int bid = blockIdx.x;
  const int b = bid >> 6;
  const int j0 = (bid & 63) * 16;
  const int t = threadIdx.x, g = t >> 6, lane = t & 63;
  for (int i = t; i < FIN * HH; i += 256) WL[i] = Wg[i];
  for (int rr = 0; rr < 4; rr++) {
    const int row = j0 + g * 4 + rr;
    float2 xv = ((const float2*)(x + ((size_t)b * NN + row) * FIN))[lane];
    __syncthreads();
    xr[g][2 * lane] = xv.x; xr[g][2 * lane + 1] = xv.y;
    __syncthreads();
    float acc = 0.f;
    #pragma unroll 8
    for (int f = 0; f < FIN; f++) acc += xr[g][f] * WL[f * HH + lane];
    float sc = dinv[b * NN + row] * acc;
    unsigned short bv = f2b(sc);
    xs[((size_t)b * NN + row) * HH + lane] = bv;
    xst[((size_t)b * HH + lane) * NN + row] = bv;
  }
}

// ---------------------------------------------------------------------------
// k_gcn: h = relu(dinv_i * (A@xs + xs_i) + b_gcn)  via bf16 MFMA (W=64)
// grid = B*16 (64 rows each), 256 threads = 4 waves (16 rows per wave)
// ---------------------------------------------------------------------------
__global__ __launch_bounds__(256) void k_gcn(const unsigned short* __restrict__ Abf,
    const unsigned short* __restrict__ xst, const unsigned short* __restrict__ xs,
    const float* __restrict__ dinv, const float* __restrict__ bgcn,
    float* __restrict__ h) {
  const int bid = blockIdx.x;
  const int b = bid >> 4;
  const int m0 = (bid & 15) * 64;
  const int t = threadIdx.x, wv = t >> 6, lane = t & 63, l15 = lane & 15, q = lane >> 4;
  const int mb = m0 + wv * 16;
  const unsigned short* Ab = Abf + (size_t)b * NN * NN;
  floatx4 acc[4];
  #pragma unroll
  for (int u = 0; u < 4; u++) acc[u] = zf4();
  for (int k0 = 0; k0 < NN; k0 += 32) {
    short8 af = *(const short8*)(Ab + (size_t)(mb + l15) * NN + k0 + q * 8);
    #pragma unroll
    for (int u = 0; u < 4; u++) {
      short8 bf = *(const short8*)(xst + ((size_t)b * HH + u * 16 + l15) * NN + k0 + q * 8);
      acc[u] = __builtin_amdgcn_mfma_f32_16x16x32_bf16(af, bf, acc[u], 0, 0, 0);
    }
  }
  #pragma unroll
  for (int r = 0; r < 4; r++) {
    const int i = mb + q * 4 + r;
    const float dv = dinv[b * NN + i];
    #pragma unroll
    for (int u = 0; u < 4; u++) {
      const int c = u * 16 + l15;
      float xsv = b2f(xs[((size_t)b * NN + i) * HH + c]);
      float v = dv * (acc[u][r] + xsv) + bgcn[c];
      h[((size_t)b * NN + i) * HH + c] = v > 0.f ? v : 0.f;
    }
  }
}

// ---------------------------------------------------------------------------
// k_unary: unary = h@W_unary + b_unary; e_k = exp(-|(h-mean_k)/scale_k|^2);
// Q0 = softmax(unary); qmut0 = (Q0@mu)^T (bf16).  grid = B*64, 256 thr
// ---------------------------------------------------------------------------
__global__ __launch_bounds__(256) void k_unary(const float* __restrict__ h,
    const float* __restrict__ Wu, const float* __restrict__ bu,
    const float* __restrict__ means, const float* __restrict__ scales,
    const float* __restrict__ mu, float* __restrict__ unary, float* __restrict__ e2,
    float* __restrict__ Q, unsigned short* __restrict__ qmut) {
  __shared__ float WuL[HH * CC];
  __shared__ float muL[CC * CC];
  __shared__ float mnL[2][HH];
  __shared__ float isL[2][HH];
  __shared__ float buL[CC];
  __shared__ float hL[4][HH];
  __shared__ float qL[4][CC];
  const int bid = blockIdx.x;
  const int b = bid >> 6;
  const int j0 = (bid & 63) * 16;
  const int t = threadIdx.x, g = t >> 6, lane = t & 63;
  for (int i = t; i < HH * CC; i += 256) WuL[i] = Wu[i];
  for (int i = t; i < CC * CC; i += 256) muL[i] = mu[i];
  if (t < 2 * HH) { mnL[t >> 6][t & 63] = means[t]; isL[t >> 6][t & 63] = 1.0f / scales[t]; }
  if (t < CC) buL[t] = bu[t];
  __syncthreads();
  for (int rr = 0; rr < 4; rr++) {
    const int row = j0 + g * 4 + rr;
    float hv = h[((size_t)b * NN + row) * HH + lane];
    hL[g][lane] = hv;
    float ev[2];
    #pragma unroll
    for (int k = 0; k < 2; k++) {
      float d = (hv - mnL[k][lane]) * isL[k][lane];
      float ds = d * d;
      #pragma unroll
      for (int m = 1; m < 64; m <<= 1) ds += __shfl_xor(ds, m, 64);
      ev[k] = __expf(-ds);
    }
    if (lane == 0) {
      e2[((size_t)b * NN + row) * 2 + 0] = ev[0];
      e2[((size_t)b * NN + row) * 2 + 1] = ev[1];
    }
    __syncthreads();
    if (lane < CC) {
      float acc = buL[lane];
      #pragma unroll 8
      for (int f = 0; f < HH; f++) acc += hL[g][f] * WuL[f * CC + lane];
      unary[((size_t)b * NN + row) * CC + lane] = acc;
      float m = acc;
      #pragma unroll
      for (int mm = 1; mm < 32; mm <<= 1) m = fmaxf(m, __shfl_xor(m, mm, 64));
      float ex = __expf(acc - m);
      float s = ex;
      #pragma unroll
      for (int mm = 1; mm < 32; mm <<= 1) s += __shfl_xor(s, mm, 64);
      float qv = ex / s;
      Q[((size_t)b * NN + row) * CC + lane] = qv;
      qL[g][lane] = qv;
    }
    __syncthreads();
    if (lane < CC) {
      float s2 = 0.f;
      #pragma unroll 8
      for (int c = 0; c < CC; c++) s2 += qL[g][c] * muL[c * CC + lane];
      qmut[((size_t)b * CC + lane) * NN + row] = f2b(s2);
    }
    __syncthreads();
  }
}

// ---------------------------------------------------------------------------
// k_pair: P[i,j] = bf16( (rowbits_i & colbits_j != 0) ? kw0*e_i0*e_j0 + kw1*e_i1*e_j1 : 0 )
// grid = B*8*4 (128 i-rows x 256 j-cols), 256 threads (one j each)
// ---------------------------------------------------------------------------
__global__ __launch_bounds__(256) void k_pair(const uint32_t* __restrict__ rowbits,
    const uint32_t* __restrict__ colbits, const float* __restrict__ e2,
    const float* __restrict__ kwp, unsigned short* __restrict__ P) {
  __shared__ uint32_t rwL[128 * 32];
  __shared__ float eaL[128][2];
  const int bid = blockIdx.x;                 // b*32 + it*4 + jt
  const int b = bid >> 5, it = (bid >> 2) & 7, jt = bid & 3;
  const int i0 = it * 128, j0 = jt * 256;
  const int t = threadIdx.x;
  #pragma unroll
  for (int x = 0; x < 16; x++)
    rwL[x * 256 + t] = rowbits[((size_t)b * NN + i0) * 32 + x * 256 + t];
  const float kw0 = kwp[0], kw1 = kwp[1];
  if (t < 128) {
    eaL[t][0] = kw0 * e2[((size_t)b * NN + i0 + t) * 2 + 0];
    eaL[t][1] = kw1 * e2[((size_t)b * NN + i0 + t) * 2 + 1];
  }
  const int j = j0 + t;
  uint32_t cb[32];
  #pragma unroll
  for (int w = 0; w < 32; w++) cb[w] = colbits[((size_t)b * NN + j) * 32 + w];
  const float ej0 = e2[((size_t)b * NN + j) * 2 + 0];
  const float ej1 = e2[((size_t)b * NN + j) * 2 + 1];
  __syncthreads();
  unsigned short* Pr = P + (size_t)b * NN * NN + (size_t)i0 * NN + j;
  for (int i = 0; i < 128; i++) {
    uint32_t m = 0;
    // dense random graphs: first word almost always hits -> wave-uniform early exit
    for (int w = 0; w < 32; w++) {
      m |= rwL[i * 32 + w] & cb[w];
      if (__all(m != 0)) break;
    }
    float sv = m ? (eaL[i][0] * ej0 + eaL[i][1] * ej1) : 0.f;
    Pr[(size_t)i * NN] = f2b(sv);
  }
}

// ---------------------------------------------------------------------------
// k_crf: msg = P @ qin^T(bf16); Q = softmax((unary+msg)*2); writes Q(fp32),
// qtb = Q^T(bf16), qout = (Q@mu)^T(bf16).  grid = B*16, 256 thr = 4 waves
// ---------------------------------------------------------------------------
__global__ __launch_bounds__(256) void k_crf(const unsigned short* __restrict__ P,
    const unsigned short* __restrict__ qin, const float* __restrict__ unary,
    const float* __restrict__ mu, float* __restrict__ Q,
    unsigned short* __restrict__ qtb, unsigned short* __restrict__ qout) {
  __shared__ float muL[CC * CC];
  __shared__ float Qs[64 * CC];
  const int bid = blockIdx.x;
  const int b = bid >> 4;
  const int m0 = (bid & 15) * 64;
  const int t = threadIdx.x, wv = t >> 6, lane = t & 63, l15 = lane & 15, q = lane >> 4;
  const int mb = m0 + wv * 16;
  for (int i = t; i < CC * CC; i += 256) muL[i] = mu[i];
  const unsigned short* Pb = P + (size_t)b * NN * NN;
  floatx4 acc[2];
  acc[0] = zf4(); acc[1] = zf4();
  for (int k0 = 0; k0 < NN; k0 += 32) {
    short8 af = *(const short8*)(Pb + (size_t)(mb + l15) * NN + k0 + q * 8);
    #pragma unroll
    for (int u = 0; u < 2; u++) {
      short8 bf = *(const short8*)(qin + ((size_t)b * CC + u * 16 + l15) * NN + k0 + q * 8);
      acc[u] = __builtin_amdgcn_mfma_f32_16x16x32_bf16(af, bf, acc[u], 0, 0, 0);
    }
  }
  #pragma unroll
  for (int r = 0; r < 4; r++) {
    const int i = mb + q * 4 + r;
    float lg0 = (unary[((size_t)b * NN + i) * CC + l15] + acc[0][r]) * 2.0f;
    float lg1 = (unary[((size_t)b * NN + i) * CC + 16 + l15] + acc[1][r]) * 2.0f;
    float m = fmaxf(lg0, lg1);
    #pragma unroll
    for (int mm = 1; mm < 16; mm <<= 1) m = fmaxf(m, __shfl_xor(m, mm, 64));
    float e0 = __expf(lg0 - m), e1 = __expf(lg1 - m);
    float s = e0 + e1;
    #pragma unroll
    for (int mm = 1; mm < 16; mm <<= 1) s += __shfl_xor(s, mm, 64);
    float inv = 1.0f / s;
    float q0 = e0 * inv, q1 = e1 * inv;
    Q[((size_t)b * NN + i) * CC + l15] = q0;
    Q[((size_t)b * NN + i) * CC + 16 + l15] = q1;
    qtb[((size_t)b * CC + l15) * NN + i] = f2b(q0);
    qtb[((size_t)b * CC + 16 + l15) * NN + i] = f2b(q1);
    Qs[(wv * 16 + q * 4 + r) * CC + l15] = q0;
    Qs[(wv * 16 + q * 4 + r) * CC + 16 + l15] = q1;
  }
  __syncthreads();
  #pragma unroll
  for (int x = 0; x < 8; x++) {
    int idx = x * 256 + t;
    int il = idx >> 5, cn = idx & 31;
    float s2 = 0.f;
    #pragma unroll 8
    for (int c = 0; c < CC; c++) s2 += Qs[il * CC + c] * muL[c * CC + cn];
    qout[((size_t)b * CC + cn) * NN + m0 + il] = f2b(s2);
  }
}

// ---------------------------------------------------------------------------
// k_adjq: adjQ = A @ Q  (bf16 MFMA, W=32). grid = B*16, 256 thr
// ---------------------------------------------------------------------------
__global__ __launch_bounds__(256) void k_adjq(const unsigned short* __restrict__ Abf,
    const unsigned short* __restrict__ qtb, float* __restrict__ adjQ) {
  const int bid = blockIdx.x;
  const int b = bid >> 4;
  const int m0 = (bid & 15) * 64;
  const int t = threadIdx.x, wv = t >> 6, lane = t & 63, l15 = lane & 15, q = lane >> 4;
  const int mb = m0 + wv * 16;
  const unsigned short* Ab = Abf + (size_t)b * NN * NN;
  floatx4 acc[2];
  acc[0] = zf4(); acc[1] = zf4();
  for (int k0 = 0; k0 < NN; k0 += 32) {
    short8 af = *(const short8*)(Ab + (size_t)(mb + l15) * NN + k0 + q * 8);
    #pragma unroll
    for (int u = 0; u < 2; u++) {
      short8 bf = *(const short8*)(qtb + ((size_t)b * CC + u * 16 + l15) * NN + k0 + q * 8);
      acc[u] = __builtin_amdgcn_mfma_f32_16x16x32_bf16(af, bf, acc[u], 0, 0, 0);
    }
  }
  #pragma unroll
  for (int r = 0; r < 4; r++) {
    const int i = mb + q * 4 + r;
    #pragma unroll
    for (int u = 0; u < 2; u++)
      adjQ[((size_t)b * NN + i) * CC + u * 16 + l15] = acc[u][r];
  }
}

// ---------------------------------------------------------------------------
// pooling helpers
// ---------------------------------------------------------------------------
__global__ __launch_bounds__(256) void k_zero(float* __restrict__ p, int n) {
  int i = blockIdx.x * 256 + threadIdx.x;
  if (i < n) p[i] = 0.f;
}

// x_pooled[b,c,h] += sum_j Q[j,c]*h[j,h].  grid = B*4 (j-chunks of 256)
__global__ __launch_bounds__(256) void k_xpool(const float* __restrict__ Q,
    const float* __restrict__ h, float* __restrict__ xpool) {
  const int bid = blockIdx.x;
  const int b = bid >> 2, jc = bid & 3;
  const int t = threadIdx.x, hh = t & 63, cg = t >> 6; // cg uniform per wave
  float acc[8] = {0, 0, 0, 0, 0, 0, 0, 0};
  for (int jj = 0; jj < 256; jj++) {
    const int j = jc * 256 + jj;
    float hv = h[((size_t)b * NN + j) * HH + hh];
    const float* qr = Q + ((size_t)b * NN + j) * CC + cg * 8;
    #pragma unroll
    for (int k = 0; k < 8; k++) acc[k] += qr[k] * hv;
  }
  #pragma unroll
  for (int k = 0; k < 8; k++)
    atomicAdd(&xpool[((size_t)b * CC + cg * 8 + k) * HH + hh], acc[k]);
}

// adj_pooled[b,c,d] += sum_j Q[j,c]*adjQ[j,d].  grid = B*4
__global__ __launch_bounds__(256) void k_adjp(const float* __restrict__ Q,
    const float* __restrict__ adjQ, float* __restrict__ adjp) {
  const int bid = blockIdx.x;
  const int b = bid >> 2, jc = bid & 3;
  const int t = threadIdx.x, d = t & 31, cg = t >> 5;
  float acc[4] = {0, 0, 0, 0};
  for (int jj = 0; jj < 256; jj++) {
    const int j = jc * 256 + jj;
    float av = adjQ[((size_t)b * NN + j) * CC + d];
    const float* qr = Q + ((size_t)b * NN + j) * CC + cg * 4;
    #pragma unroll
    for (int k = 0; k < 4; k++) acc[k] += qr[k] * av;
  }
  #pragma unroll
  for (int k = 0; k < 4; k++)
    atomicAdd(&adjp[((size_t)b * CC + cg * 4 + k) * CC + d], acc[k]);
}

__global__ __launch_bounds__(256) void k_out(const float* __restrict__ xp,
    const float* __restrict__ ap, float* __restrict__ out) {
  int i = blockIdx.x * 256 + threadIdx.x;
  if (i < NB * CC * HH) out[i] = xp[i];
  else if (i < NB * CC * HH + NB * CC * CC) out[i] = ap[i - NB * CC * HH];
}

// ---------------------------------------------------------------------------
extern "C" void kernel_launch(void* const* d_in, const int* in_sizes, int n_in,
                              void* d_out, int out_size, void* d_ws, size_t ws_size,
                              hipStream_t stream) {
  (void)in_sizes; (void)n_in; (void)out_size;
  const float* x      = (const float*)d_in[0];
  const int*   adj    = (const int*)d_in[1];
  const float* Wg     = (const float*)d_in[2];
  const float* bg     = (const float*)d_in[3];
  const float* Wu     = (const float*)d_in[4];
  const float* bu     = (const float*)d_in[5];
  const float* means  = (const float*)d_in[6];
  const float* scales = (const float*)d_in[7];
  const float* kw     = (const float*)d_in[8];
  const float* mu     = (const float*)d_in[9];

  char* ws = (char*)d_ws;
  size_t off = 0;
  auto alloc = [&](size_t bytes) { char* p = ws + off; off += (bytes + 255) & ~(size_t)255; return p; };
  unsigned short* Abf   = (unsigned short*)alloc((size_t)NB * NN * NN * 2);
  unsigned short* P     = (unsigned short*)alloc((size_t)NB * NN * NN * 2);
  uint32_t*       rbits = (uint32_t*)alloc((size_t)NB * NN * 32 * 4);
  uint32_t*       cbits = (uint32_t*)alloc((size_t)NB * NN * 32 * 4);
  float*          dinv  = (float*)alloc((size_t)NB * NN * 4);
  unsigned short* xs    = (unsigned short*)alloc((size_t)NB * NN * HH * 2);
  unsigned short* xst   = (unsigned short*)alloc((size_t)NB * HH * NN * 2);
  float*          h     = (float*)alloc((size_t)NB * NN * HH * 4);
  float*          unary = (float*)alloc((size_t)NB * NN * CC * 4);
  float*          e2    = (float*)alloc((size_t)NB * NN * 2 * 4);
  unsigned short* qmA   = (unsigned short*)alloc((size_t)NB * CC * NN * 2);
  unsigned short* qmB   = (unsigned short*)alloc((size_t)NB * CC * NN * 2);
  float*          Q     = (float*)alloc((size_t)NB * NN * CC * 4);
  unsigned short* qtb   = (unsigned short*)alloc((size_t)NB * CC * NN * 2);
  float*          adjQ  = (float*)alloc((size_t)NB * NN * CC * 4);
  float*          xpool = (float*)alloc((size_t)NB * CC * HH * 4);
  float*          adjp  = (float*)alloc((size_t)NB * CC * CC * 4);
  if (off > ws_size) return;  // workspace too small: fail visibly

  k_convert<<<NB * NN, 256, 0, stream>>>(adj, Abf, rbits, dinv);
  k_colbits<<<NB * 16, 256, 0, stream>>>(adj, cbits);
  k_xw<<<NB * 64, 256, 0, stream>>>(x, Wg, dinv, xs, xst);
  k_gcn<<<NB * 16, 256, 0, stream>>>(Abf, xst, xs, dinv, bg, h);
  k_unary<<<NB * 64, 256, 0, stream>>>(h, Wu, bu, means, scales, mu, unary, e2, Q, qmA);
  k_pair<<<NB * 32, 256, 0, stream>>>(rbits, cbits, e2, kw, P);
  // 5 CRF iterations, ping-pong qmut buffers
  k_crf<<<NB * 16, 256, 0, stream>>>(P, qmA, unary, mu, Q, qtb, qmB);
  k_crf<<<NB * 16, 256, 0, stream>>>(P, qmB, unary, mu, Q, qtb, qmA);
  k_crf<<<NB * 16, 256, 0, stream>>>(P, qmA, unary, mu, Q, qtb, qmB);
  k_crf<<<NB * 16, 256, 0, stream>>>(P, qmB, unary, mu, Q, qtb, qmA);
  k_crf<<<NB * 16, 256, 0, stream>>>(P, qmA, unary, mu, Q, qtb, qmB);
  k_adjq<<<NB * 16, 256, 0, stream>>>(Abf, qtb, adjQ);
  k_zero<<<(NB * CC * (HH + CC) + 255) / 256, 256, 0, stream>>>(xpool, NB * CC * (HH + CC));
  k_xpool<<<NB * 4, 256, 0, stream>>>(Q, h, xpool);
  k_adjp<<<NB * 4, 256, 0, stream>>>(Q, adjQ, adjp);
  k_out<<<(NB * CC * (HH + CC) + 255) / 256, 256, 0, stream>>>(xpool, adjp, (float*)d_out);
}

// Round 4
// 510.673 us; speedup vs baseline: 1.1734x; 1.1734x over previous
//
#include <hip/hip_runtime.h>
#include <stdint.h>

#define NB  32     // B
#define NN  1024   // N
#define FIN 128
#define HH  64
#define CC  32
#define ZCAP 16
#define NITER 5

using short8  = __attribute__((ext_vector_type(8))) short;
using floatx4 = __attribute__((ext_vector_type(4))) float;

__device__ inline float b2f(unsigned short u) {
  union { uint32_t i; float f; } v; v.i = ((uint32_t)u) << 16; return v.f;
}
__device__ inline unsigned short f2b(float f) {
  union { uint32_t i; float f; } v; v.f = f;
  uint32_t r = v.i + 0x7FFFu + ((v.i >> 16) & 1u);
  return (unsigned short)(r >> 16);
}
__device__ inline floatx4 zf4() { floatx4 v = {0.f, 0.f, 0.f, 0.f}; return v; }

// ---------------------------------------------------------------------------
// k_wcvt: Wgt[h][f] = bf16(Wg[f][h]); Wut[c][f] = bf16(Wu[f][c]). 1 block.
// ---------------------------------------------------------------------------
__global__ __launch_bounds__(256) void k_wcvt(const float* __restrict__ Wg,
    const float* __restrict__ Wu, unsigned short* __restrict__ Wgt,
    unsigned short* __restrict__ Wut) {
  const int t = threadIdx.x;
  for (int idx = t; idx < HH * FIN; idx += 256) {
    int hh = idx >> 7, f = idx & 127;
    Wgt[idx] = f2b(Wg[f * HH + hh]);
  }
  for (int idx = t; idx < CC * HH; idx += 256) {
    int c = idx >> 6, f = idx & 63;
    Wut[idx] = f2b(Wu[f * CC + c]);
  }
}

// ---------------------------------------------------------------------------
// k_bits: adj(int32) -> rowbits + dinv + zcnt=0. One WAVE per row; each lane
// loops 4 int4 loads to cover all 1024 columns (R2/R3 bug: covered only 256).
// grid = B*N/4 blocks, 256 threads (4 waves = 4 rows)
// ---------------------------------------------------------------------------
__global__ __launch_bounds__(256) void k_bits(const int* __restrict__ adj,
    uint32_t* __restrict__ rowbits, float* __restrict__ dinv,
    int* __restrict__ zcnt) {
  __shared__ uint32_t rw[4][32];
  const int t = threadIdx.x, g = t >> 6, lane = t & 63;
  if (lane < 32) rw[g][lane] = 0u;
  __syncthreads();
  const size_t row = (size_t)blockIdx.x * 4 + g;
  int s = 0;
  #pragma unroll
  for (int rep = 0; rep < 4; rep++) {
    int4 a = ((const int4*)(adj + row * NN))[rep * 64 + lane];   // cols 256*rep + 4*lane ..+3
    int b0 = (a.x != 0), b1 = (a.y != 0), b2 = (a.z != 0), b3 = (a.w != 0);
    uint32_t nib = ((uint32_t)(b0 | (b1 << 1) | (b2 << 2) | (b3 << 3))) << ((lane & 7) * 4);
    atomicOr(&rw[g][rep * 8 + (lane >> 3)], nib);
    s += b0 + b1 + b2 + b3;
  }
  #pragma unroll
  for (int m = 1; m < 64; m <<= 1) s += __shfl_xor(s, m, 64);
  __syncthreads();
  if (lane < 32) rowbits[row * 32 + lane] = rw[g][lane];
  if (lane == 0) { dinv[row] = rsqrtf((float)s + 1.0f); zcnt[row] = 0; }
}

// ---------------------------------------------------------------------------
// k_cbits: colbits = bit-transpose(rowbits). 64 KB LDS, two 512-row halves.
// grid = B*4 (256 cols each)
// ---------------------------------------------------------------------------
__global__ __launch_bounds__(256) void k_cbits(const uint32_t* __restrict__ rowbits,
    uint32_t* __restrict__ colbits) {
  __shared__ uint32_t rbL[512 * 32];   // 64 KB
  const int bid = blockIdx.x;
  const int b = bid >> 2, jt = bid & 3;
  const int t = threadIdx.x;
  const int j = jt * 256 + t, jw = j >> 5, jb = j & 31;
  uint32_t out[32];
  for (int half = 0; half < 2; half++) {
    const uint32_t* src = rowbits + ((size_t)b * NN + half * 512) * 32;
    __syncthreads();
    for (int idx = t; idx < 512 * 32; idx += 256) rbL[idx] = src[idx];
    __syncthreads();
    for (int w = 0; w < 16; w++) {
      uint32_t acc = 0;
      #pragma unroll
      for (int r = 0; r < 32; r++)
        acc |= ((rbL[(w * 32 + r) * 32 + jw] >> jb) & 1u) << r;
      out[half * 16 + w] = acc;
    }
  }
  uint4* dst = (uint4*)(colbits + ((size_t)b * NN + j) * 32);
  #pragma unroll
  for (int x = 0; x < 8; x++) {
    uint4 v; v.x = out[4*x]; v.y = out[4*x+1]; v.z = out[4*x+2]; v.w = out[4*x+3];
    dst[x] = v;
  }
}

// ---------------------------------------------------------------------------
// k_xw (MFMA): xs[n][h] = bf16(dinv_n * (x[n,:] @ Wg)); xst[h][n] transposed.
// ---------------------------------------------------------------------------
__global__ __launch_bounds__(256) void k_xw(const float* __restrict__ x,
    const unsigned short* __restrict__ Wgt, const float* __restrict__ dinv,
    unsigned short* __restrict__ xs, unsigned short* __restrict__ xst) {
  const int bid = blockIdx.x;
  const int b = bid >> 4;
  const int m0 = (bid & 15) * 64;
  const int t = threadIdx.x, wv = t >> 6, lane = t & 63, l15 = lane & 15, q = lane >> 4;
  const int mb = m0 + wv * 16;
  floatx4 acc[4];
  #pragma unroll
  for (int u = 0; u < 4; u++) acc[u] = zf4();
  #pragma unroll
  for (int k0 = 0; k0 < FIN; k0 += 32) {
    const float4* xp = (const float4*)(x + ((size_t)b * NN + mb + l15) * FIN + k0 + q * 8);
    float4 a0 = xp[0], a1 = xp[1];
    short8 af;
    af[0] = (short)f2b(a0.x); af[1] = (short)f2b(a0.y);
    af[2] = (short)f2b(a0.z); af[3] = (short)f2b(a0.w);
    af[4] = (short)f2b(a1.x); af[5] = (short)f2b(a1.y);
    af[6] = (short)f2b(a1.z); af[7] = (short)f2b(a1.w);
    #pragma unroll
    for (int u = 0; u < 4; u++) {
      short8 bf = *(const short8*)(Wgt + (u * 16 + l15) * FIN + k0 + q * 8);
      acc[u] = __builtin_amdgcn_mfma_f32_16x16x32_bf16(af, bf, acc[u], 0, 0, 0);
    }
  }
  #pragma unroll
  for (int r = 0; r < 4; r++) {
    const int i = mb + q * 4 + r;
    const float dv = dinv[b * NN + i];
    #pragma unroll
    for (int u = 0; u < 4; u++) {
      const int c = u * 16 + l15;
      unsigned short bv = f2b(dv * acc[u][r]);
      xs[((size_t)b * NN + i) * HH + c] = bv;
      xst[((size_t)b * HH + c) * NN + i] = bv;
    }
  }
}

// ---------------------------------------------------------------------------
// k_gcn: h = relu(dinv_i*(A@xs + xs_i) + bg), A expanded from rowbits.
// Fused: e2[i][k] = exp(-|(h_i-mean_k)/scale_k|^2).
// ---------------------------------------------------------------------------
__global__ __launch_bounds__(256) void k_gcn(const uint32_t* __restrict__ rowbits,
    const unsigned short* __restrict__ xst, const unsigned short* __restrict__ xs,
    const float* __restrict__ dinv, const float* __restrict__ bg,
    const float* __restrict__ means, const float* __restrict__ scales,
    float* __restrict__ h, float* __restrict__ e2) {
  const int bid = blockIdx.x;
  const int b = bid >> 4;
  const int m0 = (bid & 15) * 64;
  const int t = threadIdx.x, wv = t >> 6, lane = t & 63, l15 = lane & 15, q = lane >> 4;
  const int mb = m0 + wv * 16;
  floatx4 acc[4];
  #pragma unroll
  for (int u = 0; u < 4; u++) acc[u] = zf4();
  const uint32_t* rbrow = rowbits + ((size_t)b * NN + mb + l15) * 32;
  for (int k0 = 0; k0 < NN; k0 += 32) {
    uint32_t sh = rbrow[k0 >> 5] >> (q * 8);
    short8 af;
    #pragma unroll
    for (int jj = 0; jj < 8; jj++)
      af[jj] = (short)(((sh >> jj) & 1u) ? 0x3F80 : 0);
    #pragma unroll
    for (int u = 0; u < 4; u++) {
      short8 bf = *(const short8*)(xst + ((size_t)b * HH + u * 16 + l15) * NN + k0 + q * 8);
      acc[u] = __builtin_amdgcn_mfma_f32_16x16x32_bf16(af, bf, acc[u], 0, 0, 0);
    }
  }
  float bgc[4], mn0[4], mn1[4], is0[4], is1[4];
  #pragma unroll
  for (int u = 0; u < 4; u++) {
    const int c = u * 16 + l15;
    bgc[u] = bg[c];
    mn0[u] = means[c];        is0[u] = 1.0f / scales[c];
    mn1[u] = means[HH + c];   is1[u] = 1.0f / scales[HH + c];
  }
  #pragma unroll
  for (int r = 0; r < 4; r++) {
    const int i = mb + q * 4 + r;
    const float dv = dinv[b * NN + i];
    float dd0 = 0.f, dd1 = 0.f;
    #pragma unroll
    for (int u = 0; u < 4; u++) {
      const int c = u * 16 + l15;
      float xsv = b2f(xs[((size_t)b * NN + i) * HH + c]);
      float v = dv * (acc[u][r] + xsv) + bgc[u];
      v = v > 0.f ? v : 0.f;
      h[((size_t)b * NN + i) * HH + c] = v;
      float t0 = (v - mn0[u]) * is0[u]; dd0 += t0 * t0;
      float t1 = (v - mn1[u]) * is1[u]; dd1 += t1 * t1;
    }
    #pragma unroll
    for (int m = 1; m < 16; m <<= 1) {
      dd0 += __shfl_xor(dd0, m, 64);
      dd1 += __shfl_xor(dd1, m, 64);
    }
    if (l15 == 0) {
      e2[((size_t)b * NN + i) * 2 + 0] = __expf(-dd0);
      e2[((size_t)b * NN + i) * 2 + 1] = __expf(-dd1);
    }
  }
}

// ---------------------------------------------------------------------------
// k_un (MFMA): unary = h @ W_unary + bu.
// ---------------------------------------------------------------------------
__global__ __launch_bounds__(256) void k_un(const float* __restrict__ h,
    const unsigned short* __restrict__ Wut, const float* __restrict__ bu,
    float* __restrict__ unary) {
  const int bid = blockIdx.x;
  const int b = bid >> 4;
  const int m0 = (bid & 15) * 64;
  const int t = threadIdx.x, wv = t >> 6, lane = t & 63, l15 = lane & 15, q = lane >> 4;
  const int mb = m0 + wv * 16;
  floatx4 acc[2];
  acc[0] = zf4(); acc[1] = zf4();
  #pragma unroll
  for (int k0 = 0; k0 < HH; k0 += 32) {
    const float4* hp = (const float4*)(h + ((size_t)b * NN + mb + l15) * HH + k0 + q * 8);
    float4 a0 = hp[0], a1 = hp[1];
    short8 af;
    af[0] = (short)f2b(a0.x); af[1] = (short)f2b(a0.y);
    af[2] = (short)f2b(a0.z); af[3] = (short)f2b(a0.w);
    af[4] = (short)f2b(a1.x); af[5] = (short)f2b(a1.y);
    af[6] = (short)f2b(a1.z); af[7] = (short)f2b(a1.w);
    #pragma unroll
    for (int u = 0; u < 2; u++) {
      short8 bf = *(const short8*)(Wut + (u * 16 + l15) * HH + k0 + q * 8);
      acc[u] = __builtin_amdgcn_mfma_f32_16x16x32_bf16(af, bf, acc[u], 0, 0, 0);
    }
  }
  #pragma unroll
  for (int r = 0; r < 4; r++) {
    const int i = mb + q * 4 + r;
    #pragma unroll
    for (int u = 0; u < 2; u++) {
      const int c = u * 16 + l15;
      unary[((size_t)b * NN + i) * CC + c] = acc[u][r] + bu[c];
    }
  }
}

// ---------------------------------------------------------------------------
// k_zscan: rows of (A^2)==0 -> zcnt/zidx. grid = B*8
// ---------------------------------------------------------------------------
__global__ __launch_bounds__(256) void k_zscan(const uint32_t* __restrict__ rowbits,
    const uint32_t* __restrict__ colbits, int* __restrict__ zcnt,
    int* __restrict__ zidx) {
  __shared__ uint32_t rwL[128 * 32];   // 16 KB
  const int bid = blockIdx.x;
  const int b = bid >> 3, it = bid & 7;
  const int i0 = it * 128;
  const int t = threadIdx.x;
  #pragma unroll
  for (int x = 0; x < 16; x++)
    rwL[x * 256 + t] = rowbits[((size_t)b * NN + i0) * 32 + x * 256 + t];
  __syncthreads();
  for (int jc = 0; jc < 4; jc++) {
    const int j = jc * 256 + t;
    uint32_t cb[32];
    const uint4* cbp = (const uint4*)(colbits + ((size_t)b * NN + j) * 32);
    #pragma unroll
    for (int x = 0; x < 8; x++) {
      uint4 v = cbp[x];
      cb[4*x] = v.x; cb[4*x+1] = v.y; cb[4*x+2] = v.z; cb[4*x+3] = v.w;
    }
    for (int i = 0; i < 128; i++) {
      uint32_t m = 0;
      for (int w = 0; w < 32; w++) {
        m |= rwL[i * 32 + w] & cb[w];
        if (__all(m != 0)) break;
      }
      if (m == 0) {
        int old = atomicAdd(&zcnt[b * NN + i0 + i], 1);
        if (old < ZCAP) zidx[(size_t)(b * NN + i0 + i) * ZCAP + old] = j;
      }
    }
  }
}

// ---------------------------------------------------------------------------
// k_qinit: Q0 = softmax(unary). One node per thread, grid = B*N/256
// ---------------------------------------------------------------------------
__global__ __launch_bounds__(256) void k_qinit(const float* __restrict__ unary,
    float* __restrict__ Q) {
  const int gid = blockIdx.x * 256 + threadIdx.x;   // b*N + n
  float lg[CC];
  const float4* urow = (const float4*)(unary + (size_t)gid * CC);
  #pragma unroll
  for (int c4 = 0; c4 < 8; c4++) {
    float4 v = urow[c4];
    lg[c4*4] = v.x; lg[c4*4+1] = v.y; lg[c4*4+2] = v.z; lg[c4*4+3] = v.w;
  }
  float mx = lg[0];
  #pragma unroll
  for (int c = 1; c < CC; c++) mx = fmaxf(mx, lg[c]);
  float s = 0.f;
  #pragma unroll
  for (int c = 0; c < CC; c++) { lg[c] = __expf(lg[c] - mx); s += lg[c]; }
  float inv = 1.f / s;
  float4* qo = (float4*)(Q + (size_t)gid * CC);
  #pragma unroll
  for (int c4 = 0; c4 < 8; c4++) {
    float4 v;
    v.x = lg[c4*4] * inv; v.y = lg[c4*4+1] * inv;
    v.z = lg[c4*4+2] * inv; v.w = lg[c4*4+3] * inv;
    qo[c4] = v;
  }
}

// ---------------------------------------------------------------------------
// k_t: T[b][k][d] = sum_j e2[b,j,k] * Q[b,j,d].  grid = B, 256 thr.
// ---------------------------------------------------------------------------
__global__ __launch_bounds__(256) void k_t(const float* __restrict__ e2,
    const float* __restrict__ Q, float* __restrict__ T) {
  __shared__ float part[4][64];
  const int b = blockIdx.x;
  const int t = threadIdx.x, g = t >> 6, kd = t & 63, k = kd >> 5, d = kd & 31;
  const float* e2b = e2 + (size_t)b * NN * 2;
  const float* Qb  = Q + (size_t)b * NN * CC;
  float s = 0.f;
  for (int jj = 0; jj < 256; jj++) {
    const int j = g * 256 + jj;
    s += e2b[j * 2 + k] * Qb[j * CC + d];
  }
  part[g][kd] = s;
  __syncthreads();
  if (t < 64) T[b * 64 + t] = part[0][t] + part[1][t] + part[2][t] + part[3][t];
}

// ---------------------------------------------------------------------------
// k_s: S[b][k][c] = kw_k * sum_d T[b][k][d] * mu[d][c].  grid = B, 64 thr.
// ---------------------------------------------------------------------------
__global__ __launch_bounds__(64) void k_s(const float* __restrict__ T,
    const float* __restrict__ mu, const float* __restrict__ kwp,
    float* __restrict__ S) {
  const int b = blockIdx.x;
  const int t = threadIdx.x, k = t >> 5, c = t & 31;
  float s = 0.f;
  #pragma unroll 8
  for (int d = 0; d < CC; d++) s += T[b * 64 + k * 32 + d] * mu[d * CC + c];
  S[b * 64 + t] = ((k == 0) ? kwp[0] : kwp[1]) * s;
}

// ---------------------------------------------------------------------------
// k_upd: lg = unary + e0*S0 + e1*S1 - corrections; Q = softmax(lg*2).
// ---------------------------------------------------------------------------
__global__ __launch_bounds__(256) void k_upd(const float* __restrict__ unary,
    const float* __restrict__ e2, const float* __restrict__ S,
    const int* __restrict__ zcnt, const int* __restrict__ zidx,
    const uint32_t* __restrict__ rowbits, const uint32_t* __restrict__ colbits,
    const float* __restrict__ mu, const float* __restrict__ kwp,
    const float* __restrict__ Qin, float* __restrict__ Qout,
    unsigned short* __restrict__ qtb) {
  __shared__ float muL[CC * CC];
  const int gid = blockIdx.x * 256 + threadIdx.x;   // b*N + n
  const int b = gid >> 10, n = gid & 1023;
  for (int i = threadIdx.x; i < CC * CC; i += 256) muL[i] = mu[i];
  __syncthreads();
  const float e0 = e2[(size_t)gid * 2 + 0];
  const float e1 = e2[(size_t)gid * 2 + 1];
  float lg[CC];
  {
    const float4* urow = (const float4*)(unary + (size_t)gid * CC);
    const float4* S0 = (const float4*)(S + b * 64);
    const float4* S1 = (const float4*)(S + b * 64 + 32);
    #pragma unroll
    for (int c4 = 0; c4 < 8; c4++) {
      float4 uv = urow[c4], s0 = S0[c4], s1 = S1[c4];
      lg[c4*4]   = uv.x + e0 * s0.x + e1 * s1.x;
      lg[c4*4+1] = uv.y + e0 * s0.y + e1 * s1.y;
      lg[c4*4+2] = uv.z + e0 * s0.z + e1 * s1.z;
      lg[c4*4+3] = uv.w + e0 * s0.w + e1 * s1.w;
    }
  }
  const int zc = zcnt[gid];
  if (zc > 0) {
    const float kw0 = kwp[0], kw1 = kwp[1];
    if (zc <= ZCAP) {
      for (int z = 0; z < zc; z++) {
        const int j = zidx[(size_t)gid * ZCAP + z];
        const float w = kw0 * e0 * e2[((size_t)b * NN + j) * 2 + 0]
                      + kw1 * e1 * e2[((size_t)b * NN + j) * 2 + 1];
        const float* qj = Qin + ((size_t)b * NN + j) * CC;
        for (int d = 0; d < CC; d++) {
          const float wq = w * qj[d];
          #pragma unroll 8
          for (int c = 0; c < CC; c++) lg[c] -= wq * muL[d * CC + c];
        }
      }
    } else {  // dense fallback (never triggers for this input)
      const uint32_t* rbi = rowbits + (size_t)gid * 32;
      for (int j = 0; j < NN; j++) {
        uint32_t m = 0;
        const uint32_t* cbj = colbits + ((size_t)b * NN + j) * 32;
        for (int w32 = 0; w32 < 32; w32++) m |= rbi[w32] & cbj[w32];
        if (m == 0) {
          const float w = kw0 * e0 * e2[((size_t)b * NN + j) * 2 + 0]
                        + kw1 * e1 * e2[((size_t)b * NN + j) * 2 + 1];
          const float* qj = Qin + ((size_t)b * NN + j) * CC;
          for (int d = 0; d < CC; d++) {
            const float wq = w * qj[d];
            #pragma unroll 8
            for (int c = 0; c < CC; c++) lg[c] -= wq * muL[d * CC + c];
          }
        }
      }
    }
  }
  float mx = lg[0];
  #pragma unroll
  for (int c = 1; c < CC; c++) mx = fmaxf(mx, lg[c]);
  float s = 0.f;
  #pragma unroll
  for (int c = 0; c < CC; c++) { lg[c] = __expf((lg[c] - mx) * 2.0f); s += lg[c]; }
  float inv = 1.f / s;
  float4* qo = (float4*)(Qout + (size_t)gid * CC);
  #pragma unroll
  for (int c4 = 0; c4 < 8; c4++) {
    float4 v;
    v.x = lg[c4*4] * inv; v.y = lg[c4*4+1] * inv;
    v.z = lg[c4*4+2] * inv; v.w = lg[c4*4+3] * inv;
    qo[c4] = v;
  }
  #pragma unroll
  for (int c = 0; c < CC; c++)
    qtb[((size_t)b * CC + c) * NN + n] = f2b(lg[c] * inv);
}

// ---------------------------------------------------------------------------
// k_adjq: adjQ = A @ Q (A from rowbits, Q from qtb bf16). grid = B*16
// ---------------------------------------------------------------------------
__global__ __launch_bounds__(256) void k_adjq(const uint32_t* __restrict__ rowbits,
    const unsigned short* __restrict__ qtb, float* __restrict__ adjQ) {
  const int bid = blockIdx.x;
  const int b = bid >> 4;
  const int m0 = (bid & 15) * 64;
  const int t = threadIdx.x, wv = t >> 6, lane = t & 63, l15 = lane & 15, q = lane >> 4;
  const int mb = m0 + wv * 16;
  floatx4 acc[2];
  acc[0] = zf4(); acc[1] = zf4();
  const uint32_t* rbrow = rowbits + ((size_t)b * NN + mb + l15) * 32;
  for (int k0 = 0; k0 < NN; k0 += 32) {
    uint32_t sh = rbrow[k0 >> 5] >> (q * 8);
    short8 af;
    #pragma unroll
    for (int jj = 0; jj < 8; jj++)
      af[jj] = (short)(((sh >> jj) & 1u) ? 0x3F80 : 0);
    #pragma unroll
    for (int u = 0; u < 2; u++) {
      short8 bf = *(const short8*)(qtb + ((size_t)b * CC + u * 16 + l15) * NN + k0 + q * 8);
      acc[u] = __builtin_amdgcn_mfma_f32_16x16x32_bf16(af, bf, acc[u], 0, 0, 0);
    }
  }
  #pragma unroll
  for (int r = 0; r < 4; r++) {
    const int i = mb + q * 4 + r;
    #pragma unroll
    for (int u = 0; u < 2; u++)
      adjQ[((size_t)b * NN + i) * CC + u * 16 + l15] = acc[u][r];
  }
}

// ---------------------------------------------------------------------------
// pooling: accumulate straight into d_out (zeroed first)
// ---------------------------------------------------------------------------
__global__ __launch_bounds__(256) void k_zero(float* __restrict__ p, int n) {
  int i = blockIdx.x * 256 + threadIdx.x;
  if (i < n) p[i] = 0.f;
}

__global__ __launch_bounds__(256) void k_xpool(const float* __restrict__ Q,
    const float* __restrict__ h, float* __restrict__ out) {
  const int bid = blockIdx.x;
  const int b = bid >> 2, jc = bid & 3;
  const int t = threadIdx.x, hh = t & 63, cg = t >> 6;
  float acc[8] = {0, 0, 0, 0, 0, 0, 0, 0};
  for (int jj = 0; jj < 256; jj++) {
    const int j = jc * 256 + jj;
    float hv = h[((size_t)b * NN + j) * HH + hh];
    const float* qr = Q + ((size_t)b * NN + j) * CC + cg * 8;
    #pragma unroll
    for (int k = 0; k < 8; k++) acc[k] += qr[k] * hv;
  }
  #pragma unroll
  for (int k = 0; k < 8; k++)
    atomicAdd(&out[((size_t)b * CC + cg * 8 + k) * HH + hh], acc[k]);
}

__global__ __launch_bounds__(256) void k_adjp(const float* __restrict__ Q,
    const float* __restrict__ adjQ, float* __restrict__ out) {
  const int bid = blockIdx.x;
  const int b = bid >> 2, jc = bid & 3;
  const int t = threadIdx.x, d = t & 31, cg = t >> 5;
  float acc[4] = {0, 0, 0, 0};
  for (int jj = 0; jj < 256; jj++) {
    const int j = jc * 256 + jj;
    float av = adjQ[((size_t)b * NN + j) * CC + d];
    const float* qr = Q + ((size_t)b * NN + j) * CC + cg * 4;
    #pragma unroll
    for (int k = 0; k < 4; k++) acc[k] += qr[k] * av;
  }
  #pragma unroll
  for (int k = 0; k < 4; k++)
    atomicAdd(&out[(size_t)NB * CC * HH + ((size_t)b * CC + cg * 4 + k) * CC + d], acc[k]);
}

// ---------------------------------------------------------------------------
extern "C" void kernel_launch(void* const* d_in, const int* in_sizes, int n_in,
                              void* d_out, int out_size, void* d_ws, size_t ws_size,
                              hipStream_t stream) {
  (void)in_sizes; (void)n_in; (void)out_size;
  const float* x      = (const float*)d_in[0];
  const int*   adj    = (const int*)d_in[1];
  const float* Wg     = (const float*)d_in[2];
  const float* bg     = (const float*)d_in[3];
  const float* Wu     = (const float*)d_in[4];
  const float* bu     = (const float*)d_in[5];
  const float* means  = (const float*)d_in[6];
  const float* scales = (const float*)d_in[7];
  const float* kw     = (const float*)d_in[8];
  const float* mu     = (const float*)d_in[9];

  char* ws = (char*)d_ws;
  size_t off = 0;
  auto alloc = [&](size_t bytes) { char* p = ws + off; off += (bytes + 255) & ~(size_t)255; return p; };
  uint32_t*       rbits = (uint32_t*)alloc((size_t)NB * NN * 32 * 4);
  uint32_t*       cbits = (uint32_t*)alloc((size_t)NB * NN * 32 * 4);
  float*          dinv  = (float*)alloc((size_t)NB * NN * 4);
  unsigned short* Wgt   = (unsigned short*)alloc((size_t)HH * FIN * 2);
  unsigned short* Wut   = (unsigned short*)alloc((size_t)CC * HH * 2);
  unsigned short* xs    = (unsigned short*)alloc((size_t)NB * NN * HH * 2);
  unsigned short* xst   = (unsigned short*)alloc((size_t)NB * HH * NN * 2);
  float*          h     = (float*)alloc((size_t)NB * NN * HH * 4);
  float*          e2    = (float*)alloc((size_t)NB * NN * 2 * 4);
  float*          unary = (float*)alloc((size_t)NB * NN * CC * 4);
  int*            zcnt  = (int*)alloc((size_t)NB * NN * 4);
  int*            zidx  = (int*)alloc((size_t)NB * NN * ZCAP * 4);
  float*          Qa    = (float*)alloc((size_t)NB * NN * CC * 4);
  float*          Qb    = (float*)alloc((size_t)NB * NN * CC * 4);
  unsigned short* qtb   = (unsigned short*)alloc((size_t)NB * CC * NN * 2);
  float*          adjQ  = (float*)alloc((size_t)NB * NN * CC * 4);
  float*          T     = (float*)alloc((size_t)NB * 64 * 4);
  float*          S     = (float*)alloc((size_t)NB * 64 * 4);
  if (off > ws_size) return;

  float* out = (float*)d_out;
  const int out_n = NB * CC * (HH + CC);

  k_wcvt <<<1, 256, 0, stream>>>(Wg, Wu, Wgt, Wut);
  k_bits <<<NB * NN / 4, 256, 0, stream>>>(adj, rbits, dinv, zcnt);
  k_zero <<<(out_n + 255) / 256, 256, 0, stream>>>(out, out_n);
  k_cbits<<<NB * 4, 256, 0, stream>>>(rbits, cbits);
  k_xw   <<<NB * 16, 256, 0, stream>>>(x, Wgt, dinv, xs, xst);
  k_gcn  <<<NB * 16, 256, 0, stream>>>(rbits, xst, xs, dinv, bg, means, scales, h, e2);
  k_un   <<<NB * 16, 256, 0, stream>>>(h, Wut, bu, unary);
  k_zscan<<<NB * 8, 256, 0, stream>>>(rbits, cbits, zcnt, zidx);
  k_qinit<<<NB * NN / 256, 256, 0, stream>>>(unary, Qa);
  float* qin = Qa; float* qout = Qb;
  for (int it = 0; it < NITER; it++) {
    k_t  <<<NB, 256, 0, stream>>>(e2, qin, T);
    k_s  <<<NB, 64, 0, stream>>>(T, mu, kw, S);
    k_upd<<<NB * NN / 256, 256, 0, stream>>>(unary, e2, S, zcnt, zidx,
                                             rbits, cbits, mu, kw, qin, qout, qtb);
    float* tmp = qin; qin = qout; qout = tmp;
  }
  k_adjq <<<NB * 16, 256, 0, stream>>>(rbits, qtb, adjQ);
  k_xpool<<<NB * 4, 256, 0, stream>>>(qin, h, out);
  k_adjp <<<NB * 4, 256, 0, stream>>>(qin, adjQ, out);
}

// Round 5
// 479.762 us; speedup vs baseline: 1.2490x; 1.0644x over previous
//
#include <hip/hip_runtime.h>
#include <stdint.h>

#define NB  32     // B
#define NN  1024   // N
#define FIN 128
#define HH  64
#define CC  32
#define ZCAP 16
#define NITER 5

using short8  = __attribute__((ext_vector_type(8))) short;
using floatx4 = __attribute__((ext_vector_type(4))) float;

__device__ inline float b2f(unsigned short u) {
  union { uint32_t i; float f; } v; v.i = ((uint32_t)u) << 16; return v.f;
}
__device__ inline unsigned short f2b(float f) {
  union { uint32_t i; float f; } v; v.f = f;
  uint32_t r = v.i + 0x7FFFu + ((v.i >> 16) & 1u);
  return (unsigned short)(r >> 16);
}
__device__ inline floatx4 zf4() { floatx4 v = {0.f, 0.f, 0.f, 0.f}; return v; }

// ---------------------------------------------------------------------------
// k_wcvt: weight transposes to bf16 + zero d_out. 1 block.
// ---------------------------------------------------------------------------
__global__ __launch_bounds__(256) void k_wcvt(const float* __restrict__ Wg,
    const float* __restrict__ Wu, unsigned short* __restrict__ Wgt,
    unsigned short* __restrict__ Wut, float* __restrict__ out, int out_n) {
  const int t = threadIdx.x;
  for (int idx = t; idx < HH * FIN; idx += 256) {
    int hh = idx >> 7, f = idx & 127;
    Wgt[idx] = f2b(Wg[f * HH + hh]);
  }
  for (int idx = t; idx < CC * HH; idx += 256) {
    int c = idx >> 6, f = idx & 63;
    Wut[idx] = f2b(Wu[f * CC + c]);
  }
  for (int idx = t; idx < out_n; idx += 256) out[idx] = 0.f;
}

// ---------------------------------------------------------------------------
// k_bits: adj(int32) -> rowbits + dinv + zcnt=0. One WAVE per row, 4 reps of
// int4 loads covering all 1024 columns. grid = B*N/4, 256 thr
// ---------------------------------------------------------------------------
__global__ __launch_bounds__(256) void k_bits(const int* __restrict__ adj,
    uint32_t* __restrict__ rowbits, float* __restrict__ dinv,
    int* __restrict__ zcnt) {
  __shared__ uint32_t rw[4][32];
  const int t = threadIdx.x, g = t >> 6, lane = t & 63;
  if (lane < 32) rw[g][lane] = 0u;
  __syncthreads();
  const size_t row = (size_t)blockIdx.x * 4 + g;
  int s = 0;
  #pragma unroll
  for (int rep = 0; rep < 4; rep++) {
    int4 a = ((const int4*)(adj + row * NN))[rep * 64 + lane];
    int b0 = (a.x != 0), b1 = (a.y != 0), b2 = (a.z != 0), b3 = (a.w != 0);
    uint32_t nib = ((uint32_t)(b0 | (b1 << 1) | (b2 << 2) | (b3 << 3))) << ((lane & 7) * 4);
    atomicOr(&rw[g][rep * 8 + (lane >> 3)], nib);
    s += b0 + b1 + b2 + b3;
  }
  #pragma unroll
  for (int m = 1; m < 64; m <<= 1) s += __shfl_xor(s, m, 64);
  __syncthreads();
  if (lane < 32) rowbits[row * 32 + lane] = rw[g][lane];
  if (lane == 0) { dinv[row] = rsqrtf((float)s + 1.0f); zcnt[row] = 0; }
}

// ---------------------------------------------------------------------------
// k_cbits: colbits = bit-transpose(rowbits). grid = B*8 (half x jt), 256 thr
// ---------------------------------------------------------------------------
__global__ __launch_bounds__(256) void k_cbits(const uint32_t* __restrict__ rowbits,
    uint32_t* __restrict__ colbits) {
  __shared__ uint32_t rbL[512 * 32];   // 64 KB
  const int bid = blockIdx.x;
  const int b = bid >> 3, half = (bid >> 2) & 1, jt = bid & 3;
  const int t = threadIdx.x;
  const uint32_t* src = rowbits + ((size_t)b * NN + half * 512) * 32;
  for (int idx = t; idx < 512 * 32; idx += 256) rbL[idx] = src[idx];
  __syncthreads();
  const int j = jt * 256 + t, jw = j >> 5, jb = j & 31;
  uint32_t out[16];
  for (int w = 0; w < 16; w++) {
    uint32_t acc = 0;
    #pragma unroll
    for (int r = 0; r < 32; r++)
      acc |= ((rbL[(w * 32 + r) * 32 + jw] >> jb) & 1u) << r;
    out[w] = acc;
  }
  uint4* dst = (uint4*)(colbits + ((size_t)b * NN + j) * 32 + half * 16);
  #pragma unroll
  for (int x = 0; x < 4; x++) {
    uint4 v; v.x = out[4*x]; v.y = out[4*x+1]; v.z = out[4*x+2]; v.w = out[4*x+3];
    dst[x] = v;
  }
}

// ---------------------------------------------------------------------------
// k_xw (MFMA): xs[n][h] = bf16(dinv_n * (x[n,:] @ Wg)); xst[h][n] transposed.
// ---------------------------------------------------------------------------
__global__ __launch_bounds__(256) void k_xw(const float* __restrict__ x,
    const unsigned short* __restrict__ Wgt, const float* __restrict__ dinv,
    unsigned short* __restrict__ xs, unsigned short* __restrict__ xst) {
  const int bid = blockIdx.x;
  const int b = bid >> 4;
  const int m0 = (bid & 15) * 64;
  const int t = threadIdx.x, wv = t >> 6, lane = t & 63, l15 = lane & 15, q = lane >> 4;
  const int mb = m0 + wv * 16;
  floatx4 acc[4];
  #pragma unroll
  for (int u = 0; u < 4; u++) acc[u] = zf4();
  #pragma unroll
  for (int k0 = 0; k0 < FIN; k0 += 32) {
    const float4* xp = (const float4*)(x + ((size_t)b * NN + mb + l15) * FIN + k0 + q * 8);
    float4 a0 = xp[0], a1 = xp[1];
    short8 af;
    af[0] = (short)f2b(a0.x); af[1] = (short)f2b(a0.y);
    af[2] = (short)f2b(a0.z); af[3] = (short)f2b(a0.w);
    af[4] = (short)f2b(a1.x); af[5] = (short)f2b(a1.y);
    af[6] = (short)f2b(a1.z); af[7] = (short)f2b(a1.w);
    #pragma unroll
    for (int u = 0; u < 4; u++) {
      short8 bf = *(const short8*)(Wgt + (u * 16 + l15) * FIN + k0 + q * 8);
      acc[u] = __builtin_amdgcn_mfma_f32_16x16x32_bf16(af, bf, acc[u], 0, 0, 0);
    }
  }
  #pragma unroll
  for (int r = 0; r < 4; r++) {
    const int i = mb + q * 4 + r;
    const float dv = dinv[b * NN + i];
    #pragma unroll
    for (int u = 0; u < 4; u++) {
      const int c = u * 16 + l15;
      unsigned short bv = f2b(dv * acc[u][r]);
      xs[((size_t)b * NN + i) * HH + c] = bv;
      xst[((size_t)b * HH + c) * NN + i] = bv;
    }
  }
}

// ---------------------------------------------------------------------------
// k_gcnun: h = relu(dinv_i*(A@xs + xs_i) + bg) with A expanded from rowbits;
// fused e2 = exp(-dist^2) AND unary = h@Wu + bu (wave-private LDS transpose
// of the h tile feeds two more MFMA k-steps). grid = B*16, 256 thr
// ---------------------------------------------------------------------------
__global__ __launch_bounds__(256) void k_gcnun(const uint32_t* __restrict__ rowbits,
    const unsigned short* __restrict__ xst, const unsigned short* __restrict__ xs,
    const float* __restrict__ dinv, const float* __restrict__ bg,
    const float* __restrict__ means, const float* __restrict__ scales,
    const unsigned short* __restrict__ Wut, const float* __restrict__ bu,
    float* __restrict__ h, float* __restrict__ e2, float* __restrict__ unary) {
  __shared__ unsigned short hsh[4][16][72];   // 9 KB, wave-private tiles
  const int bid = blockIdx.x;
  const int b = bid >> 4;
  const int m0 = (bid & 15) * 64;
  const int t = threadIdx.x, wv = t >> 6, lane = t & 63, l15 = lane & 15, q = lane >> 4;
  const int mb = m0 + wv * 16;
  floatx4 acc[4];
  #pragma unroll
  for (int u = 0; u < 4; u++) acc[u] = zf4();
  const uint32_t* rbrow = rowbits + ((size_t)b * NN + mb + l15) * 32;
  for (int k0 = 0; k0 < NN; k0 += 32) {
    uint32_t sh = rbrow[k0 >> 5] >> (q * 8);
    short8 af;
    #pragma unroll
    for (int jj = 0; jj < 8; jj++)
      af[jj] = (short)(((sh >> jj) & 1u) ? 0x3F80 : 0);
    #pragma unroll
    for (int u = 0; u < 4; u++) {
      short8 bf = *(const short8*)(xst + ((size_t)b * HH + u * 16 + l15) * NN + k0 + q * 8);
      acc[u] = __builtin_amdgcn_mfma_f32_16x16x32_bf16(af, bf, acc[u], 0, 0, 0);
    }
  }
  float bgc[4], mn0[4], mn1[4], is0[4], is1[4];
  #pragma unroll
  for (int u = 0; u < 4; u++) {
    const int c = u * 16 + l15;
    bgc[u] = bg[c];
    mn0[u] = means[c];        is0[u] = 1.0f / scales[c];
    mn1[u] = means[HH + c];   is1[u] = 1.0f / scales[HH + c];
  }
  #pragma unroll
  for (int r = 0; r < 4; r++) {
    const int i = mb + q * 4 + r;
    const float dv = dinv[b * NN + i];
    float dd0 = 0.f, dd1 = 0.f;
    #pragma unroll
    for (int u = 0; u < 4; u++) {
      const int c = u * 16 + l15;
      float xsv = b2f(xs[((size_t)b * NN + i) * HH + c]);
      float v = dv * (acc[u][r] + xsv) + bgc[u];
      v = v > 0.f ? v : 0.f;
      h[((size_t)b * NN + i) * HH + c] = v;
      unsigned short hb = f2b(v);
      hsh[wv][q * 4 + r][c] = hb;
      float vb = b2f(hb);
      float t0 = (vb - mn0[u]) * is0[u]; dd0 += t0 * t0;
      float t1 = (vb - mn1[u]) * is1[u]; dd1 += t1 * t1;
    }
    #pragma unroll
    for (int m = 1; m < 16; m <<= 1) {
      dd0 += __shfl_xor(dd0, m, 64);
      dd1 += __shfl_xor(dd1, m, 64);
    }
    if (l15 == 0) {
      e2[((size_t)b * NN + i) * 2 + 0] = __expf(-dd0);
      e2[((size_t)b * NN + i) * 2 + 1] = __expf(-dd1);
    }
  }
  // unary = h @ Wu + bu : A-fragments from wave-private LDS tile
  floatx4 uacc[2];
  uacc[0] = zf4(); uacc[1] = zf4();
  #pragma unroll
  for (int k0 = 0; k0 < HH; k0 += 32) {
    short8 af = *(const short8*)&hsh[wv][l15][k0 + q * 8];
    #pragma unroll
    for (int u = 0; u < 2; u++) {
      short8 bf = *(const short8*)(Wut + (u * 16 + l15) * HH + k0 + q * 8);
      uacc[u] = __builtin_amdgcn_mfma_f32_16x16x32_bf16(af, bf, uacc[u], 0, 0, 0);
    }
  }
  #pragma unroll
  for (int r = 0; r < 4; r++) {
    const int i = mb + q * 4 + r;
    #pragma unroll
    for (int u = 0; u < 2; u++) {
      const int c = u * 16 + l15;
      unary[((size_t)b * NN + i) * CC + c] = uacc[u][r] + bu[c];
    }
  }
}

// ---------------------------------------------------------------------------
// k_zscan: rows of (A^2)==0 -> zcnt/zidx. grid = B*8
// ---------------------------------------------------------------------------
__global__ __launch_bounds__(256) void k_zscan(const uint32_t* __restrict__ rowbits,
    const uint32_t* __restrict__ colbits, int* __restrict__ zcnt,
    int* __restrict__ zidx) {
  __shared__ uint32_t rwL[128 * 32];   // 16 KB
  const int bid = blockIdx.x;
  const int b = bid >> 3, it = bid & 7;
  const int i0 = it * 128;
  const int t = threadIdx.x;
  #pragma unroll
  for (int x = 0; x < 16; x++)
    rwL[x * 256 + t] = rowbits[((size_t)b * NN + i0) * 32 + x * 256 + t];
  __syncthreads();
  for (int jc = 0; jc < 4; jc++) {
    const int j = jc * 256 + t;
    uint32_t cb[32];
    const uint4* cbp = (const uint4*)(colbits + ((size_t)b * NN + j) * 32);
    #pragma unroll
    for (int x = 0; x < 8; x++) {
      uint4 v = cbp[x];
      cb[4*x] = v.x; cb[4*x+1] = v.y; cb[4*x+2] = v.z; cb[4*x+3] = v.w;
    }
    for (int i = 0; i < 128; i++) {
      uint32_t m = 0;
      for (int w = 0; w < 32; w++) {
        m |= rwL[i * 32 + w] & cb[w];
        if (__all(m != 0)) break;
      }
      if (m == 0) {
        int old = atomicAdd(&zcnt[b * NN + i0 + i], 1);
        if (old < ZCAP) zidx[(size_t)(b * NN + i0 + i) * ZCAP + old] = j;
      }
    }
  }
}

// ---------------------------------------------------------------------------
// k_crf5: init softmax + all 5 mean-field iterations fused; rank-2 pairwise
// with exact zero-mask corrections. One block/batch, 1024 thr (1 node each).
// Q kept in LDS as packed bf16 pairs (stride 17 words = conflict-free).
// ---------------------------------------------------------------------------
__global__ __launch_bounds__(1024) void k_crf5(const float* __restrict__ unary,
    const float* __restrict__ e2, const float* __restrict__ kwp,
    const float* __restrict__ mu, const uint32_t* __restrict__ rowbits,
    const uint32_t* __restrict__ colbits, const int* __restrict__ zcnt,
    const int* __restrict__ zidx, float* __restrict__ Q,
    unsigned short* __restrict__ qtb) {
  __shared__ uint32_t QLu[NN * 17];    // 68 KB
  __shared__ float eLs[NN * 2];
  __shared__ float Twave[16 * 8];
  __shared__ float Tfin[64];
  __shared__ float muL[CC * CC];
  __shared__ float S[64];
  const int b = blockIdx.x;
  const int t = threadIdx.x;           // node index
  for (int i = t; i < CC * CC; i += 1024) muL[i] = mu[i];
  const float kw0 = kwp[0], kw1 = kwp[1];
  float u[CC];
  {
    const float4* urow = (const float4*)(unary + ((size_t)b * NN + t) * CC);
    #pragma unroll
    for (int c4 = 0; c4 < 8; c4++) {
      float4 v = urow[c4];
      u[c4*4] = v.x; u[c4*4+1] = v.y; u[c4*4+2] = v.z; u[c4*4+3] = v.w;
    }
  }
  const float e0 = e2[((size_t)b * NN + t) * 2 + 0];
  const float e1 = e2[((size_t)b * NN + t) * 2 + 1];
  eLs[t * 2 + 0] = e0; eLs[t * 2 + 1] = e1;
  const int zc = zcnt[b * NN + t];
  float lg[CC];
  {  // Q0 = softmax(unary)
    float mx = u[0];
    #pragma unroll
    for (int c = 1; c < CC; c++) mx = fmaxf(mx, u[c]);
    float s = 0.f;
    #pragma unroll
    for (int c = 0; c < CC; c++) { lg[c] = __expf(u[c] - mx); s += lg[c]; }
    float inv = 1.f / s;
    #pragma unroll
    for (int c = 0; c < CC; c++) lg[c] *= inv;
  }
  #pragma unroll
  for (int d2 = 0; d2 < 16; d2++)
    QLu[t * 17 + d2] = (uint32_t)f2b(lg[2*d2]) | ((uint32_t)f2b(lg[2*d2+1]) << 16);
  __syncthreads();
  const int tk = t >> 9, tdc = (t >> 7) & 3, tpart = t & 127, twv = t >> 6;
  for (int it = 0; it < NITER; it++) {
    // --- T_k[d] = sum_j e_jk * Q[j][d] ---
    float tacc[8];
    #pragma unroll
    for (int d = 0; d < 8; d++) tacc[d] = 0.f;
    for (int s8 = 0; s8 < 8; s8++) {
      int j = tpart + 128 * s8;
      float ej = eLs[j * 2 + tk];
      #pragma unroll
      for (int i2 = 0; i2 < 4; i2++) {
        uint32_t w = QLu[j * 17 + tdc * 4 + i2];
        union { uint32_t i; float f; } lo, hi;
        lo.i = w << 16; hi.i = w & 0xFFFF0000u;
        tacc[i2 * 2]     += ej * lo.f;
        tacc[i2 * 2 + 1] += ej * hi.f;
      }
    }
    #pragma unroll
    for (int m = 1; m < 64; m <<= 1) {
      #pragma unroll
      for (int d = 0; d < 8; d++) tacc[d] += __shfl_xor(tacc[d], m, 64);
    }
    if ((t & 63) == 0) {
      #pragma unroll
      for (int d = 0; d < 8; d++) Twave[twv * 8 + d] = tacc[d];
    }
    __syncthreads();
    if (t < 64) {
      int k = t >> 5, d = t & 31;
      int base = (k * 4 + (d >> 3)) * 2;
      Tfin[t] = Twave[base * 8 + (d & 7)] + Twave[(base + 1) * 8 + (d & 7)];
    }
    __syncthreads();
    if (t < 64) {  // S[k][c] = kw_k * (T_k @ mu)[c]
      int k = t >> 5, c = t & 31;
      float s = 0.f;
      #pragma unroll
      for (int d = 0; d < CC; d++) s += Tfin[k * 32 + d] * muL[d * 32 + c];
      S[t] = (k == 0 ? kw0 : kw1) * s;
    }
    __syncthreads();
    {
      const float4* S4 = (const float4*)S;
      #pragma unroll
      for (int c4 = 0; c4 < 8; c4++) {
        float4 s0 = S4[c4], s1 = S4[8 + c4];
        lg[c4*4]   = u[c4*4]   + e0 * s0.x + e1 * s1.x;
        lg[c4*4+1] = u[c4*4+1] + e0 * s0.y + e1 * s1.y;
        lg[c4*4+2] = u[c4*4+2] + e0 * s0.z + e1 * s1.z;
        lg[c4*4+3] = u[c4*4+3] + e0 * s0.w + e1 * s1.w;
      }
    }
    if (zc > 0) {
      if (zc <= ZCAP) {
        for (int z = 0; z < zc; z++) {
          int j = zidx[(size_t)(b * NN + t) * ZCAP + z];
          float w = kw0 * e0 * eLs[j * 2] + kw1 * e1 * eLs[j * 2 + 1];
          #pragma unroll
          for (int d2 = 0; d2 < 16; d2++) {
            uint32_t wq = QLu[j * 17 + d2];
            union { uint32_t i; float f; } lo, hi;
            lo.i = wq << 16; hi.i = wq & 0xFFFF0000u;
            float w0 = w * lo.f, w1 = w * hi.f;
            #pragma unroll
            for (int c = 0; c < CC; c++)
              lg[c] -= w0 * muL[(2*d2) * 32 + c] + w1 * muL[(2*d2+1) * 32 + c];
          }
        }
      } else {  // dense fallback (adversarial-only)
        const uint32_t* rbi = rowbits + ((size_t)b * NN + t) * 32;
        for (int j = 0; j < NN; j++) {
          uint32_t m = 0;
          const uint32_t* cbj = colbits + ((size_t)b * NN + j) * 32;
          for (int w32 = 0; w32 < 32; w32++) m |= rbi[w32] & cbj[w32];
          if (m == 0) {
            float w = kw0 * e0 * eLs[j * 2] + kw1 * e1 * eLs[j * 2 + 1];
            #pragma unroll
            for (int d2 = 0; d2 < 16; d2++) {
              uint32_t wq = QLu[j * 17 + d2];
              union { uint32_t i; float f; } lo, hi;
              lo.i = wq << 16; hi.i = wq & 0xFFFF0000u;
              float w0 = w * lo.f, w1 = w * hi.f;
              #pragma unroll
              for (int c = 0; c < CC; c++)
                lg[c] -= w0 * muL[(2*d2) * 32 + c] + w1 * muL[(2*d2+1) * 32 + c];
            }
          }
        }
      }
    }
    {  // softmax((u+msg)/TEMP), TEMP=0.5
      float mx = lg[0];
      #pragma unroll
      for (int c = 1; c < CC; c++) mx = fmaxf(mx, lg[c]);
      float s = 0.f;
      #pragma unroll
      for (int c = 0; c < CC; c++) { lg[c] = __expf((lg[c] - mx) * 2.0f); s += lg[c]; }
      float inv = 1.f / s;
      #pragma unroll
      for (int c = 0; c < CC; c++) lg[c] *= inv;
    }
    __syncthreads();   // all reads of QLu done before overwrite
    #pragma unroll
    for (int d2 = 0; d2 < 16; d2++)
      QLu[t * 17 + d2] = (uint32_t)f2b(lg[2*d2]) | ((uint32_t)f2b(lg[2*d2+1]) << 16);
    __syncthreads();
  }
  float4* qo = (float4*)(Q + ((size_t)b * NN + t) * CC);
  #pragma unroll
  for (int c4 = 0; c4 < 8; c4++) {
    float4 v;
    v.x = lg[c4*4]; v.y = lg[c4*4+1]; v.z = lg[c4*4+2]; v.w = lg[c4*4+3];
    qo[c4] = v;
  }
  #pragma unroll
  for (int c = 0; c < CC; c++)
    qtb[((size_t)b * CC + c) * NN + t] = f2b(lg[c]);
}

// ---------------------------------------------------------------------------
// k_adjq: adjQ = A @ Q (A from rowbits, Q from qtb bf16). grid = B*16
// ---------------------------------------------------------------------------
__global__ __launch_bounds__(256) void k_adjq(const uint32_t* __restrict__ rowbits,
    const unsigned short* __restrict__ qtb, float* __restrict__ adjQ) {
  const int bid = blockIdx.x;
  const int b = bid >> 4;
  const int m0 = (bid & 15) * 64;
  const int t = threadIdx.x, wv = t >> 6, lane = t & 63, l15 = lane & 15, q = lane >> 4;
  const int mb = m0 + wv * 16;
  floatx4 acc[2];
  acc[0] = zf4(); acc[1] = zf4();
  const uint32_t* rbrow = rowbits + ((size_t)b * NN + mb + l15) * 32;
  for (int k0 = 0; k0 < NN; k0 += 32) {
    uint32_t sh = rbrow[k0 >> 5] >> (q * 8);
    short8 af;
    #pragma unroll
    for (int jj = 0; jj < 8; jj++)
      af[jj] = (short)(((sh >> jj) & 1u) ? 0x3F80 : 0);
    #pragma unroll
    for (int u = 0; u < 2; u++) {
      short8 bf = *(const short8*)(qtb + ((size_t)b * CC + u * 16 + l15) * NN + k0 + q * 8);
      acc[u] = __builtin_amdgcn_mfma_f32_16x16x32_bf16(af, bf, acc[u], 0, 0, 0);
    }
  }
  #pragma unroll
  for (int r = 0; r < 4; r++) {
    const int i = mb + q * 4 + r;
    #pragma unroll
    for (int u = 0; u < 2; u++)
      adjQ[((size_t)b * NN + i) * CC + u * 16 + l15] = acc[u][r];
  }
}

// ---------------------------------------------------------------------------
// k_pool: bid<NB*4 -> x_pooled partials; else adj_pooled partials (atomics
// into pre-zeroed d_out). grid = B*8, 256 thr
// ---------------------------------------------------------------------------
__global__ __launch_bounds__(256) void k_pool(const float* __restrict__ Q,
    const float* __restrict__ h, const float* __restrict__ adjQ,
    float* __restrict__ out) {
  const int bid = blockIdx.x;
  const int t = threadIdx.x;
  if (bid < NB * 4) {
    const int b = bid >> 2, jc = bid & 3;
    const int hh = t & 63, cg = t >> 6;
    float acc[8] = {0, 0, 0, 0, 0, 0, 0, 0};
    for (int jj = 0; jj < 256; jj++) {
      const int j = jc * 256 + jj;
      float hv = h[((size_t)b * NN + j) * HH + hh];
      const float* qr = Q + ((size_t)b * NN + j) * CC + cg * 8;
      #pragma unroll
      for (int k = 0; k < 8; k++) acc[k] += qr[k] * hv;
    }
    #pragma unroll
    for (int k = 0; k < 8; k++)
      atomicAdd(&out[((size_t)b * CC + cg * 8 + k) * HH + hh], acc[k]);
  } else {
    const int bid2 = bid - NB * 4;
    const int b = bid2 >> 2, jc = bid2 & 3;
    const int d = t & 31, cg = t >> 5;
    float acc[4] = {0, 0, 0, 0};
    for (int jj = 0; jj < 256; jj++) {
      const int j = jc * 256 + jj;
      float av = adjQ[((size_t)b * NN + j) * CC + d];
      const float* qr = Q + ((size_t)b * NN + j) * CC + cg * 4;
      #pragma unroll
      for (int k = 0; k < 4; k++) acc[k] += qr[k] * av;
    }
    #pragma unroll
    for (int k = 0; k < 4; k++)
      atomicAdd(&out[(size_t)NB * CC * HH + ((size_t)b * CC + cg * 4 + k) * CC + d], acc[k]);
  }
}

// ---------------------------------------------------------------------------
extern "C" void kernel_launch(void* const* d_in, const int* in_sizes, int n_in,
                              void* d_out, int out_size, void* d_ws, size_t ws_size,
                              hipStream_t stream) {
  (void)in_sizes; (void)n_in; (void)out_size;
  const float* x      = (const float*)d_in[0];
  const int*   adj    = (const int*)d_in[1];
  const float* Wg     = (const float*)d_in[2];
  const float* bg     = (const float*)d_in[3];
  const float* Wu     = (const float*)d_in[4];
  const float* bu     = (const float*)d_in[5];
  const float* means  = (const float*)d_in[6];
  const float* scales = (const float*)d_in[7];
  const float* kw     = (const float*)d_in[8];
  const float* mu     = (const float*)d_in[9];

  char* ws = (char*)d_ws;
  size_t off = 0;
  auto alloc = [&](size_t bytes) { char* p = ws + off; off += (bytes + 255) & ~(size_t)255; return p; };
  uint32_t*       rbits = (uint32_t*)alloc((size_t)NB * NN * 32 * 4);
  uint32_t*       cbits = (uint32_t*)alloc((size_t)NB * NN * 32 * 4);
  float*          dinv  = (float*)alloc((size_t)NB * NN * 4);
  unsigned short* Wgt   = (unsigned short*)alloc((size_t)HH * FIN * 2);
  unsigned short* Wut   = (unsigned short*)alloc((size_t)CC * HH * 2);
  unsigned short* xs    = (unsigned short*)alloc((size_t)NB * NN * HH * 2);
  unsigned short* xst   = (unsigned short*)alloc((size_t)NB * HH * NN * 2);
  float*          h     = (float*)alloc((size_t)NB * NN * HH * 4);
  float*          e2    = (float*)alloc((size_t)NB * NN * 2 * 4);
  float*          unary = (float*)alloc((size_t)NB * NN * CC * 4);
  int*            zcnt  = (int*)alloc((size_t)NB * NN * 4);
  int*            zidx  = (int*)alloc((size_t)NB * NN * ZCAP * 4);
  float*          Q     = (float*)alloc((size_t)NB * NN * CC * 4);
  unsigned short* qtb   = (unsigned short*)alloc((size_t)NB * CC * NN * 2);
  float*          adjQ  = (float*)alloc((size_t)NB * NN * CC * 4);
  if (off > ws_size) return;

  float* out = (float*)d_out;
  const int out_n = NB * CC * (HH + CC);

  k_wcvt <<<1, 256, 0, stream>>>(Wg, Wu, Wgt, Wut, out, out_n);
  k_bits <<<NB * NN / 4, 256, 0, stream>>>(adj, rbits, dinv, zcnt);
  k_cbits<<<NB * 8, 256, 0, stream>>>(rbits, cbits);
  k_xw   <<<NB * 16, 256, 0, stream>>>(x, Wgt, dinv, xs, xst);
  k_gcnun<<<NB * 16, 256, 0, stream>>>(rbits, xst, xs, dinv, bg, means, scales,
                                       Wut, bu, h, e2, unary);
  k_zscan<<<NB * 8, 256, 0, stream>>>(rbits, cbits, zcnt, zidx);
  k_crf5 <<<NB, 1024, 0, stream>>>(unary, e2, kw, mu, rbits, cbits, zcnt, zidx, Q, qtb);
  k_adjq <<<NB * 16, 256, 0, stream>>>(rbits, qtb, adjQ);
  k_pool <<<NB * 8, 256, 0, stream>>>(Q, h, adjQ, out);
}

// Round 7
// 428.879 us; speedup vs baseline: 1.3972x; 1.1186x over previous
//
#include <hip/hip_runtime.h>
#include <stdint.h>

#define NB  32     // B
#define NN  1024   // N
#define FIN 128
#define HH  64
#define CC  32
#define ZCAP 16
#define NITER 5

using short8  = __attribute__((ext_vector_type(8))) short;
using floatx4 = __attribute__((ext_vector_type(4))) float;

__device__ inline float b2f(unsigned short u) {
  union { uint32_t i; float f; } v; v.i = ((uint32_t)u) << 16; return v.f;
}
__device__ inline unsigned short f2b(float f) {
  union { uint32_t i; float f; } v; v.f = f;
  uint32_t r = v.i + 0x7FFFu + ((v.i >> 16) & 1u);
  return (unsigned short)(r >> 16);
}
__device__ inline floatx4 zf4() { floatx4 v = {0.f, 0.f, 0.f, 0.f}; return v; }

// ---------------------------------------------------------------------------
// k_wcvt: weight transposes to bf16 + zero d_out. 1 block.
// ---------------------------------------------------------------------------
__global__ __launch_bounds__(256) void k_wcvt(const float* __restrict__ Wg,
    const float* __restrict__ Wu, unsigned short* __restrict__ Wgt,
    unsigned short* __restrict__ Wut, float* __restrict__ out, int out_n) {
  const int t = threadIdx.x;
  for (int idx = t; idx < HH * FIN; idx += 256) {
    int hh = idx >> 7, f = idx & 127;
    Wgt[idx] = f2b(Wg[f * HH + hh]);
  }
  for (int idx = t; idx < CC * HH; idx += 256) {
    int c = idx >> 6, f = idx & 63;
    Wut[idx] = f2b(Wu[f * CC + c]);
  }
  for (int idx = t; idx < out_n; idx += 256) out[idx] = 0.f;
}

// ---------------------------------------------------------------------------
// k_bits: adj(int32) -> rowbits + dinv + zcnt=0. One wave/row, 4 int4 reps.
// ---------------------------------------------------------------------------
__global__ __launch_bounds__(256) void k_bits(const int* __restrict__ adj,
    uint32_t* __restrict__ rowbits, float* __restrict__ dinv,
    int* __restrict__ zcnt) {
  __shared__ uint32_t rw[4][32];
  const int t = threadIdx.x, g = t >> 6, lane = t & 63;
  if (lane < 32) rw[g][lane] = 0u;
  __syncthreads();
  const size_t row = (size_t)blockIdx.x * 4 + g;
  int s = 0;
  #pragma unroll
  for (int rep = 0; rep < 4; rep++) {
    int4 a = ((const int4*)(adj + row * NN))[rep * 64 + lane];
    int b0 = (a.x != 0), b1 = (a.y != 0), b2 = (a.z != 0), b3 = (a.w != 0);
    uint32_t nib = ((uint32_t)(b0 | (b1 << 1) | (b2 << 2) | (b3 << 3))) << ((lane & 7) * 4);
    atomicOr(&rw[g][rep * 8 + (lane >> 3)], nib);
    s += b0 + b1 + b2 + b3;
  }
  #pragma unroll
  for (int m = 1; m < 64; m <<= 1) s += __shfl_xor(s, m, 64);
  __syncthreads();
  if (lane < 32) rowbits[row * 32 + lane] = rw[g][lane];
  if (lane == 0) { dinv[row] = rsqrtf((float)s + 1.0f); zcnt[row] = 0; }
}

// ---------------------------------------------------------------------------
// k_cbits: colbits = bit-transpose(rowbits). grid = B*8 (half x jt), 256 thr
// ---------------------------------------------------------------------------
__global__ __launch_bounds__(256) void k_cbits(const uint32_t* __restrict__ rowbits,
    uint32_t* __restrict__ colbits) {
  __shared__ uint32_t rbL[512 * 32];   // 64 KB
  const int bid = blockIdx.x;
  const int b = bid >> 3, half = (bid >> 2) & 1, jt = bid & 3;
  const int t = threadIdx.x;
  const uint32_t* src = rowbits + ((size_t)b * NN + half * 512) * 32;
  for (int idx = t; idx < 512 * 32; idx += 256) rbL[idx] = src[idx];
  __syncthreads();
  const int j = jt * 256 + t, jw = j >> 5, jb = j & 31;
  uint32_t out[16];
  for (int w = 0; w < 16; w++) {
    uint32_t acc = 0;
    #pragma unroll
    for (int r = 0; r < 32; r++)
      acc |= ((rbL[(w * 32 + r) * 32 + jw] >> jb) & 1u) << r;
    out[w] = acc;
  }
  uint4* dst = (uint4*)(colbits + ((size_t)b * NN + j) * 32 + half * 16);
  #pragma unroll
  for (int x = 0; x < 4; x++) {
    uint4 v; v.x = out[4*x]; v.y = out[4*x+1]; v.z = out[4*x+2]; v.w = out[4*x+3];
    dst[x] = v;
  }
}

// ---------------------------------------------------------------------------
// k_xw (MFMA): xs[n][h] = bf16(dinv_n * (x[n,:] @ Wg)); xst[h][n] transposed.
// ---------------------------------------------------------------------------
__global__ __launch_bounds__(256) void k_xw(const float* __restrict__ x,
    const unsigned short* __restrict__ Wgt, const float* __restrict__ dinv,
    unsigned short* __restrict__ xs, unsigned short* __restrict__ xst) {
  const int bid = blockIdx.x;
  const int b = bid >> 4;
  const int m0 = (bid & 15) * 64;
  const int t = threadIdx.x, wv = t >> 6, lane = t & 63, l15 = lane & 15, q = lane >> 4;
  const int mb = m0 + wv * 16;
  floatx4 acc[4];
  #pragma unroll
  for (int u = 0; u < 4; u++) acc[u] = zf4();
  #pragma unroll
  for (int k0 = 0; k0 < FIN; k0 += 32) {
    const float4* xp = (const float4*)(x + ((size_t)b * NN + mb + l15) * FIN + k0 + q * 8);
    float4 a0 = xp[0], a1 = xp[1];
    short8 af;
    af[0] = (short)f2b(a0.x); af[1] = (short)f2b(a0.y);
    af[2] = (short)f2b(a0.z); af[3] = (short)f2b(a0.w);
    af[4] = (short)f2b(a1.x); af[5] = (short)f2b(a1.y);
    af[6] = (short)f2b(a1.z); af[7] = (short)f2b(a1.w);
    #pragma unroll
    for (int u = 0; u < 4; u++) {
      short8 bf = *(const short8*)(Wgt + (u * 16 + l15) * FIN + k0 + q * 8);
      acc[u] = __builtin_amdgcn_mfma_f32_16x16x32_bf16(af, bf, acc[u], 0, 0, 0);
    }
  }
  #pragma unroll
  for (int r = 0; r < 4; r++) {
    const int i = mb + q * 4 + r;
    const float dv = dinv[b * NN + i];
    #pragma unroll
    for (int u = 0; u < 4; u++) {
      const int c = u * 16 + l15;
      unsigned short bv = f2b(dv * acc[u][r]);
      xs[((size_t)b * NN + i) * HH + c] = bv;
      xst[((size_t)b * HH + c) * NN + i] = bv;
    }
  }
}

// ---------------------------------------------------------------------------
// k_gcnun: h = relu(dinv_i*(A@xs + xs_i) + bg); fused e2, unary = h@Wu+bu,
// and Q0 = softmax(unary) (16-lane shuffle softmax). grid = B*16, 256 thr
// ---------------------------------------------------------------------------
__global__ __launch_bounds__(256) void k_gcnun(const uint32_t* __restrict__ rowbits,
    const unsigned short* __restrict__ xst, const unsigned short* __restrict__ xs,
    const float* __restrict__ dinv, const float* __restrict__ bg,
    const float* __restrict__ means, const float* __restrict__ scales,
    const unsigned short* __restrict__ Wut, const float* __restrict__ bu,
    float* __restrict__ h, float* __restrict__ e2, float* __restrict__ unary,
    float* __restrict__ Q0) {
  __shared__ unsigned short hsh[4][16][72];   // 9 KB, wave-private tiles
  const int bid = blockIdx.x;
  const int b = bid >> 4;
  const int m0 = (bid & 15) * 64;
  const int t = threadIdx.x, wv = t >> 6, lane = t & 63, l15 = lane & 15, q = lane >> 4;
  const int mb = m0 + wv * 16;
  floatx4 acc[4];
  #pragma unroll
  for (int u = 0; u < 4; u++) acc[u] = zf4();
  const uint32_t* rbrow = rowbits + ((size_t)b * NN + mb + l15) * 32;
  for (int k0 = 0; k0 < NN; k0 += 32) {
    uint32_t sh = rbrow[k0 >> 5] >> (q * 8);
    short8 af;
    #pragma unroll
    for (int jj = 0; jj < 8; jj++)
      af[jj] = (short)(((sh >> jj) & 1u) ? 0x3F80 : 0);
    #pragma unroll
    for (int u = 0; u < 4; u++) {
      short8 bf = *(const short8*)(xst + ((size_t)b * HH + u * 16 + l15) * NN + k0 + q * 8);
      acc[u] = __builtin_amdgcn_mfma_f32_16x16x32_bf16(af, bf, acc[u], 0, 0, 0);
    }
  }
  float bgc[4], mn0[4], mn1[4], is0[4], is1[4];
  #pragma unroll
  for (int u = 0; u < 4; u++) {
    const int c = u * 16 + l15;
    bgc[u] = bg[c];
    mn0[u] = means[c];        is0[u] = 1.0f / scales[c];
    mn1[u] = means[HH + c];   is1[u] = 1.0f / scales[HH + c];
  }
  #pragma unroll
  for (int r = 0; r < 4; r++) {
    const int i = mb + q * 4 + r;
    const float dv = dinv[b * NN + i];
    float dd0 = 0.f, dd1 = 0.f;
    #pragma unroll
    for (int u = 0; u < 4; u++) {
      const int c = u * 16 + l15;
      float xsv = b2f(xs[((size_t)b * NN + i) * HH + c]);
      float v = dv * (acc[u][r] + xsv) + bgc[u];
      v = v > 0.f ? v : 0.f;
      h[((size_t)b * NN + i) * HH + c] = v;
      unsigned short hb = f2b(v);
      hsh[wv][q * 4 + r][c] = hb;
      float vb = b2f(hb);
      float t0 = (vb - mn0[u]) * is0[u]; dd0 += t0 * t0;
      float t1 = (vb - mn1[u]) * is1[u]; dd1 += t1 * t1;
    }
    #pragma unroll
    for (int m = 1; m < 16; m <<= 1) {
      dd0 += __shfl_xor(dd0, m, 64);
      dd1 += __shfl_xor(dd1, m, 64);
    }
    if (l15 == 0) {
      e2[((size_t)b * NN + i) * 2 + 0] = __expf(-dd0);
      e2[((size_t)b * NN + i) * 2 + 1] = __expf(-dd1);
    }
  }
  // unary = h @ Wu + bu (A-fragments from wave-private LDS tile), then Q0
  floatx4 uacc[2];
  uacc[0] = zf4(); uacc[1] = zf4();
  #pragma unroll
  for (int k0 = 0; k0 < HH; k0 += 32) {
    short8 af = *(const short8*)&hsh[wv][l15][k0 + q * 8];
    #pragma unroll
    for (int u = 0; u < 2; u++) {
      short8 bf = *(const short8*)(Wut + (u * 16 + l15) * HH + k0 + q * 8);
      uacc[u] = __builtin_amdgcn_mfma_f32_16x16x32_bf16(af, bf, uacc[u], 0, 0, 0);
    }
  }
  const float bu0 = bu[l15], bu1 = bu[16 + l15];
  #pragma unroll
  for (int r = 0; r < 4; r++) {
    const int i = mb + q * 4 + r;
    float a0 = uacc[0][r] + bu0;
    float a1 = uacc[1][r] + bu1;
    unary[((size_t)b * NN + i) * CC + l15] = a0;
    unary[((size_t)b * NN + i) * CC + 16 + l15] = a1;
    float mx = fmaxf(a0, a1);
    #pragma unroll
    for (int m = 1; m < 16; m <<= 1) mx = fmaxf(mx, __shfl_xor(mx, m, 64));
    float x0 = __expf(a0 - mx), x1 = __expf(a1 - mx);
    float s = x0 + x1;
    #pragma unroll
    for (int m = 1; m < 16; m <<= 1) s += __shfl_xor(s, m, 64);
    float inv = 1.f / s;
    Q0[((size_t)b * NN + i) * CC + l15] = x0 * inv;
    Q0[((size_t)b * NN + i) * CC + 16 + l15] = x1 * inv;
  }
}

// ---------------------------------------------------------------------------
// k_zscan: rows of (A^2)==0 -> zcnt/zidx. grid = B*8
// ---------------------------------------------------------------------------
__global__ __launch_bounds__(256) void k_zscan(const uint32_t* __restrict__ rowbits,
    const uint32_t* __restrict__ colbits, int* __restrict__ zcnt,
    int* __restrict__ zidx) {
  __shared__ uint32_t rwL[128 * 32];   // 16 KB
  const int bid = blockIdx.x;
  const int b = bid >> 3, it = bid & 7;
  const int i0 = it * 128;
  const int t = threadIdx.x;
  #pragma unroll
  for (int x = 0; x < 16; x++)
    rwL[x * 256 + t] = rowbits[((size_t)b * NN + i0) * 32 + x * 256 + t];
  __syncthreads();
  for (int jc = 0; jc < 4; jc++) {
    const int j = jc * 256 + t;
    uint32_t cb[32];
    const uint4* cbp = (const uint4*)(colbits + ((size_t)b * NN + j) * 32);
    #pragma unroll
    for (int x = 0; x < 8; x++) {
      uint4 v = cbp[x];
      cb[4*x] = v.x; cb[4*x+1] = v.y; cb[4*x+2] = v.z; cb[4*x+3] = v.w;
    }
    for (int i = 0; i < 128; i++) {
      uint32_t m = 0;
      for (int w = 0; w < 32; w++) {
        m |= rwL[i * 32 + w] & cb[w];
        if (__all(m != 0)) break;
      }
      if (m == 0) {
        int old = atomicAdd(&zcnt[b * NN + i0 + i], 1);
        if (old < ZCAP) zidx[(size_t)(b * NN + i0 + i) * ZCAP + old] = j;
      }
    }
  }
}

// ---------------------------------------------------------------------------
// k_titer: per-block partial T. grid = B*4 (256-node slice), 256 thr.
// thread t: (k,d) = ((t>>5)&1, t&31), j-subslice = t>>6 (64 nodes).
// ---------------------------------------------------------------------------
__global__ __launch_bounds__(256) void k_titer(const float* __restrict__ e2,
    const float* __restrict__ Q, float* __restrict__ Tpart) {
  __shared__ float part[4][64];
  const int bid = blockIdx.x;
  const int b = bid >> 2, qd = bid & 3;
  const int t = threadIdx.x, kd = t & 63, d = t & 31, k = (t >> 5) & 1, sub = t >> 6;
  const float* e2b = e2 + (size_t)b * NN * 2;
  const float* Qb  = Q + (size_t)b * NN * CC;
  const int j0 = qd * 256 + sub * 64;
  float s = 0.f;
  #pragma unroll 8
  for (int jj = 0; jj < 64; jj++) {
    const int j = j0 + jj;
    s += e2b[j * 2 + k] * Qb[j * CC + d];
  }
  part[sub][kd] = s;
  __syncthreads();
  if (t < 64)
    Tpart[(size_t)bid * 64 + t] = part[0][t] + part[1][t] + part[2][t] + part[3][t];
}

// ---------------------------------------------------------------------------
// k_supd: S = kw*(T@mu) from the 4 partials; per-node logit update + exact
// corrections + softmax*2. grid = B*4 (256 nodes), 256 thr. Ping-pong Q.
// ---------------------------------------------------------------------------
__global__ __launch_bounds__(256) void k_supd(const float* __restrict__ unary,
    const float* __restrict__ e2, const float* __restrict__ Tpart,
    const float* __restrict__ mu, const float* __restrict__ kwp,
    const int* __restrict__ zcnt, const int* __restrict__ zidx,
    const uint32_t* __restrict__ rowbits, const uint32_t* __restrict__ colbits,
    const float* __restrict__ Qin, float* __restrict__ Qout,
    unsigned short* __restrict__ qtb, int last) {
  __shared__ float muL[CC * CC];
  __shared__ float Ts[64];
  __shared__ float S[64];
  const int bid = blockIdx.x;
  const int b = bid >> 2, seg = bid & 3;
  const int t = threadIdx.x;
  for (int i = t; i < CC * CC; i += 256) muL[i] = mu[i];
  if (t < 64)
    Ts[t] = Tpart[(size_t)(b * 4 + 0) * 64 + t] + Tpart[(size_t)(b * 4 + 1) * 64 + t]
          + Tpart[(size_t)(b * 4 + 2) * 64 + t] + Tpart[(size_t)(b * 4 + 3) * 64 + t];
  __syncthreads();
  if (t < 64) {
    const int k = t >> 5, c = t & 31;
    float s = 0.f;
    #pragma unroll 8
    for (int d = 0; d < CC; d++) s += Ts[k * 32 + d] * muL[d * 32 + c];
    S[t] = ((k == 0) ? kwp[0] : kwp[1]) * s;
  }
  __syncthreads();
  const int n = seg * 256 + t;
  const int gid = b * NN + n;
  const float e0 = e2[(size_t)gid * 2 + 0];
  const float e1 = e2[(size_t)gid * 2 + 1];
  float lg[CC];
  {
    const float4* urow = (const float4*)(unary + (size_t)gid * CC);
    const float4* S0 = (const float4*)S;
    const float4* S1 = (const float4*)(S + 32);
    #pragma unroll
    for (int c4 = 0; c4 < 8; c4++) {
      float4 uv = urow[c4], s0 = S0[c4], s1 = S1[c4];
      lg[c4*4]   = uv.x + e0 * s0.x + e1 * s1.x;
      lg[c4*4+1] = uv.y + e0 * s0.y + e1 * s1.y;
      lg[c4*4+2] = uv.z + e0 * s0.z + e1 * s1.z;
      lg[c4*4+3] = uv.w + e0 * s0.w + e1 * s1.w;
    }
  }
  const int zc = zcnt[gid];
  if (zc > 0) {
    const float kw0 = kwp[0], kw1 = kwp[1];
    if (zc <= ZCAP) {
      for (int z = 0; z < zc; z++) {
        const int j = zidx[(size_t)gid * ZCAP + z];
        const float w = kw0 * e0 * e2[((size_t)b * NN + j) * 2 + 0]
                      + kw1 * e1 * e2[((size_t)b * NN + j) * 2 + 1];
        const float* qj = Qin + ((size_t)b * NN + j) * CC;
        for (int d = 0; d < CC; d++) {
          const float wq = w * qj[d];
          #pragma unroll 8
          for (int c = 0; c < CC; c++) lg[c] -= wq * muL[d * CC + c];
        }
      }
    } else {  // dense fallback (never triggers for this input)
      const uint32_t* rbi = rowbits + (size_t)gid * 32;
      for (int j = 0; j < NN; j++) {
        uint32_t m = 0;
        const uint32_t* cbj = colbits + ((size_t)b * NN + j) * 32;
        for (int w32 = 0; w32 < 32; w32++) m |= rbi[w32] & cbj[w32];
        if (m == 0) {
          const float w = kw0 * e0 * e2[((size_t)b * NN + j) * 2 + 0]
                        + kw1 * e1 * e2[((size_t)b * NN + j) * 2 + 1];
          const float* qj = Qin + ((size_t)b * NN + j) * CC;
          for (int d = 0; d < CC; d++) {
            const float wq = w * qj[d];
            #pragma unroll 8
            for (int c = 0; c < CC; c++) lg[c] -= wq * muL[d * CC + c];
          }
        }
      }
    }
  }
  float mx = lg[0];
  #pragma unroll
  for (int c = 1; c < CC; c++) mx = fmaxf(mx, lg[c]);
  float s = 0.f;
  #pragma unroll
  for (int c = 0; c < CC; c++) { lg[c] = __expf((lg[c] - mx) * 2.0f); s += lg[c]; }
  float inv = 1.f / s;
  float4* qo = (float4*)(Qout + (size_t)gid * CC);
  #pragma unroll
  for (int c4 = 0; c4 < 8; c4++) {
    float4 v;
    v.x = lg[c4*4] * inv; v.y = lg[c4*4+1] * inv;
    v.z = lg[c4*4+2] * inv; v.w = lg[c4*4+3] * inv;
    qo[c4] = v;
  }
  if (last) {
    #pragma unroll
    for (int c = 0; c < CC; c++)
      qtb[((size_t)b * CC + c) * NN + n] = f2b(lg[c] * inv);
  }
}

// ---------------------------------------------------------------------------
// k_adjq: adjQ = A @ Q (A from rowbits, Q from qtb bf16). grid = B*16
// ---------------------------------------------------------------------------
__global__ __launch_bounds__(256) void k_adjq(const uint32_t* __restrict__ rowbits,
    const unsigned short* __restrict__ qtb, float* __restrict__ adjQ) {
  const int bid = blockIdx.x;
  const int b = bid >> 4;
  const int m0 = (bid & 15) * 64;
  const int t = threadIdx.x, wv = t >> 6, lane = t & 63, l15 = lane & 15, q = lane >> 4;
  const int mb = m0 + wv * 16;
  floatx4 acc[2];
  acc[0] = zf4(); acc[1] = zf4();
  const uint32_t* rbrow = rowbits + ((size_t)b * NN + mb + l15) * 32;
  for (int k0 = 0; k0 < NN; k0 += 32) {
    uint32_t sh = rbrow[k0 >> 5] >> (q * 8);
    short8 af;
    #pragma unroll
    for (int jj = 0; jj < 8; jj++)
      af[jj] = (short)(((sh >> jj) & 1u) ? 0x3F80 : 0);
    #pragma unroll
    for (int u = 0; u < 2; u++) {
      short8 bf = *(const short8*)(qtb + ((size_t)b * CC + u * 16 + l15) * NN + k0 + q * 8);
      acc[u] = __builtin_amdgcn_mfma_f32_16x16x32_bf16(af, bf, acc[u], 0, 0, 0);
    }
  }
  #pragma unroll
  for (int r = 0; r < 4; r++) {
    const int i = mb + q * 4 + r;
    #pragma unroll
    for (int u = 0; u < 2; u++)
      adjQ[((size_t)b * NN + i) * CC + u * 16 + l15] = acc[u][r];
  }
}

// ---------------------------------------------------------------------------
// k_pool: bid<NB*4 -> x_pooled partials; else adj_pooled partials (atomics
// into pre-zeroed d_out). grid = B*8, 256 thr
// ---------------------------------------------------------------------------
__global__ __launch_bounds__(256) void k_pool(const float* __restrict__ Q,
    const float* __restrict__ h, const float* __restrict__ adjQ,
    float* __restrict__ out) {
  const int bid = blockIdx.x;
  const int t = threadIdx.x;
  if (bid < NB * 4) {
    const int b = bid >> 2, jc = bid & 3;
    const int hh = t & 63, cg = t >> 6;
    float acc[8] = {0, 0, 0, 0, 0, 0, 0, 0};
    for (int jj = 0; jj < 256; jj++) {
      const int j = jc * 256 + jj;
      float hv = h[((size_t)b * NN + j) * HH + hh];
      const float* qr = Q + ((size_t)b * NN + j) * CC + cg * 8;
      #pragma unroll
      for (int k = 0; k < 8; k++) acc[k] += qr[k] * hv;
    }
    #pragma unroll
    for (int k = 0; k < 8; k++)
      atomicAdd(&out[((size_t)b * CC + cg * 8 + k) * HH + hh], acc[k]);
  } else {
    const int bid2 = bid - NB * 4;
    const int b = bid2 >> 2, jc = bid2 & 3;
    const int d = t & 31, cg = t >> 5;
    float acc[4] = {0, 0, 0, 0};
    for (int jj = 0; jj < 256; jj++) {
      const int j = jc * 256 + jj;
      float av = adjQ[((size_t)b * NN + j) * CC + d];
      const float* qr = Q + ((size_t)b * NN + j) * CC + cg * 4;
      #pragma unroll
      for (int k = 0; k < 4; k++) acc[k] += qr[k] * av;
    }
    #pragma unroll
    for (int k = 0; k < 4; k++)
      atomicAdd(&out[(size_t)NB * CC * HH + ((size_t)b * CC + cg * 4 + k) * CC + d], acc[k]);
  }
}

// ---------------------------------------------------------------------------
extern "C" void kernel_launch(void* const* d_in, const int* in_sizes, int n_in,
                              void* d_out, int out_size, void* d_ws, size_t ws_size,
                              hipStream_t stream) {
  (void)in_sizes; (void)n_in; (void)out_size;
  const float* x      = (const float*)d_in[0];
  const int*   adj    = (const int*)d_in[1];
  const float* Wg     = (const float*)d_in[2];
  const float* bg     = (const float*)d_in[3];
  const float* Wu     = (const float*)d_in[4];
  const float* bu     = (const float*)d_in[5];
  const float* means  = (const float*)d_in[6];
  const float* scales = (const float*)d_in[7];
  const float* kw     = (const float*)d_in[8];
  const float* mu     = (const float*)d_in[9];

  char* ws = (char*)d_ws;
  size_t off = 0;
  auto alloc = [&](size_t bytes) { char* p = ws + off; off += (bytes + 255) & ~(size_t)255; return p; };
  uint32_t*       rbits = (uint32_t*)alloc((size_t)NB * NN * 32 * 4);
  uint32_t*       cbits = (uint32_t*)alloc((size_t)NB * NN * 32 * 4);
  float*          dinv  = (float*)alloc((size_t)NB * NN * 4);
  unsigned short* Wgt   = (unsigned short*)alloc((size_t)HH * FIN * 2);
  unsigned short* Wut   = (unsigned short*)alloc((size_t)CC * HH * 2);
  unsigned short* xs    = (unsigned short*)alloc((size_t)NB * NN * HH * 2);
  unsigned short* xst   = (unsigned short*)alloc((size_t)NB * HH * NN * 2);
  float*          h     = (float*)alloc((size_t)NB * NN * HH * 4);
  float*          e2    = (float*)alloc((size_t)NB * NN * 2 * 4);
  float*          unary = (float*)alloc((size_t)NB * NN * CC * 4);
  int*            zcnt  = (int*)alloc((size_t)NB * NN * 4);
  int*            zidx  = (int*)alloc((size_t)NB * NN * ZCAP * 4);
  float*          Qa    = (float*)alloc((size_t)NB * NN * CC * 4);
  float*          Qb    = (float*)alloc((size_t)NB * NN * CC * 4);
  unsigned short* qtb   = (unsigned short*)alloc((size_t)NB * CC * NN * 2);
  float*          adjQ  = (float*)alloc((size_t)NB * NN * CC * 4);
  float*          Tpart = (float*)alloc((size_t)NB * 4 * 64 * 4);
  if (off > ws_size) return;

  float* out = (float*)d_out;
  const int out_n = NB * CC * (HH + CC);

  k_wcvt <<<1, 256, 0, stream>>>(Wg, Wu, Wgt, Wut, out, out_n);
  k_bits <<<NB * NN / 4, 256, 0, stream>>>(adj, rbits, dinv, zcnt);
  k_cbits<<<NB * 8, 256, 0, stream>>>(rbits, cbits);
  k_xw   <<<NB * 16, 256, 0, stream>>>(x, Wgt, dinv, xs, xst);
  k_gcnun<<<NB * 16, 256, 0, stream>>>(rbits, xst, xs, dinv, bg, means, scales,
                                       Wut, bu, h, e2, unary, Qa);
  k_zscan<<<NB * 8, 256, 0, stream>>>(rbits, cbits, zcnt, zidx);
  float* qin = Qa; float* qout = Qb;
  for (int it = 0; it < NITER; it++) {
    k_titer<<<NB * 4, 256, 0, stream>>>(e2, qin, Tpart);
    k_supd <<<NB * 4, 256, 0, stream>>>(unary, e2, Tpart, mu, kw, zcnt, zidx,
                                        rbits, cbits, qin, qout, qtb,
                                        it == NITER - 1 ? 1 : 0);
    float* tmp = qin; qin = qout; qout = tmp;
  }
  k_adjq <<<NB * 16, 256, 0, stream>>>(rbits, qtb, adjQ);
  k_pool <<<NB * 8, 256, 0, stream>>>(qin, h, adjQ, out);
}